// Round 1
// baseline (3684.734 us; speedup 1.0000x reference)
//
#include <hip/hip_runtime.h>
#include <hip/hip_bf16.h>

#define N_USERS 100000
#define E_HYPER 50000
#define NNZ_E   800000
#define T_STEPS 8
#define DIM     64
#define IDXM    0xFFFFF

#define TR_BLOCKS 1024
#define GE_BLOCKS 782
#define GN_BLOCKS 1563
#define B_BLOCKS  3125
#define FU_BLOCKS 1024

typedef __bf16 bf16x8 __attribute__((ext_vector_type(8)));
typedef float  f32x4  __attribute__((ext_vector_type(4)));

// ---------------------------------------------------------------------------
__device__ __forceinline__ float ld_in(const void* p, size_t i, int f32)
{
    return f32 ? ((const float*)p)[i]
               : __bfloat162float(((const __hip_bfloat16*)p)[i]);
}

__device__ __forceinline__ int dec(int v, int tag)
{
    return ((v >> 20) == tag) ? (v & IDXM) : -1;
}

// carry access: f32-in-dout(f=1) | f32-in-ws | bf16-in-dout
__device__ __forceinline__ float ld_carry(void* out, float* cws, size_t i,
                                          int f, int use_ws)
{
    if (f) return ((float*)out)[i];
    if (use_ws) return cws[i];
    return __bfloat162float(((__hip_bfloat16*)out)[i]);
}
__device__ __forceinline__ void st_carry(void* out, float* cws, size_t i,
                                         int f, int use_ws, int wr, float v)
{
    if (f) { ((float*)out)[i] = v; return; }
    if (use_ws) {
        cws[i] = v;
        if (wr) ((__hip_bfloat16*)out)[i] = __float2bfloat16(v);
        return;
    }
    ((__hip_bfloat16*)out)[i] = __float2bfloat16(v);
}

// ---------------------------------------------------------------------------
// Kernel 0: input dtype detector (proven: resolves f=0 for bf16 inputs)
// ---------------------------------------------------------------------------
__global__ void k_detect(const unsigned short* __restrict__ raw, int* __restrict__ flag)
{
    __shared__ int cnt;
    if (threadIdx.x == 0) cnt = 0;
    __syncthreads();
    int c = 0;
    for (int i = threadIdx.x; i < 4096; i += blockDim.x) {
        int e = (raw[i] >> 7) & 0xFF;
        if (e > 126) c++;
    }
    atomicAdd(&cnt, c);
    __syncthreads();
    if (threadIdx.x == 0) *flag = (cnt > 64) ? 1 : 0;
}

// ---------------------------------------------------------------------------
// Kernel 0b: params -> fp32 staging
// st: W[0,4096) b[4096,4160) w1[4160,8256) b1[8256,8320) w2[8320,8384) b2[8384]
// ---------------------------------------------------------------------------
__global__ void k_convert_params(
    const void* W, const void* b, const void* w1, const void* b1,
    const void* w2, const void* b2, const int* __restrict__ flag,
    float* __restrict__ st)
{
    int f = *flag;
    int i = blockIdx.x * blockDim.x + threadIdx.x;
    if (i < 4096)          st[i] = ld_in(W,  i,        f);
    else if (i < 4160)     st[i] = ld_in(b,  i - 4096, f);
    else if (i < 8256)     st[i] = ld_in(w1, i - 4160, f);
    else if (i < 8320)     st[i] = ld_in(b1, i - 8256, f);
    else if (i < 8384)     st[i] = ld_in(w2, i - 8320, f);
    else if (i == 8384)    st[i] = ld_in(b2, 0,        f);
}

// ---------------------------------------------------------------------------
// build body: tagged linked lists. head value = (tag<<20)|i.
// ---------------------------------------------------------------------------
__device__ __forceinline__ void build_body(
    const int* __restrict__ nodes, const int* __restrict__ hyper,
    int* __restrict__ he, int* __restrict__ ne,
    int* __restrict__ hn, int* __restrict__ nn, int tag, int i)
{
    if (i >= NNZ_E) return;
    int tv = (tag << 20) | i;
    ne[i] = atomicExch(&he[hyper[i]], tv);
    nn[i] = atomicExch(&hn[nodes[i]], tv);
}

// ---------------------------------------------------------------------------
// fuse body: carry = softmax-blend(carry, dy) via MFMA 16x16x32 bf16
// (R5/R7-proven fragment layout; b2 cancels in 2-way softmax)
// ---------------------------------------------------------------------------
__device__ __forceinline__ void fu_body(
    void* __restrict__ dout, float* __restrict__ cws,
    const float* __restrict__ dy_buf, const float* __restrict__ st,
    int f, int use_ws, int write_out, int bid, int nblocks, int tid)
{
    float* cf = f ? (float*)dout : (use_ws ? cws : (float*)0);
    __hip_bfloat16* cb = (__hip_bfloat16*)dout;

    int lane = tid & 63;
    int quad = lane >> 4;
    int m    = lane & 15;

    bf16x8 bw[4][2];
    float b1v[4], w2v[4];
#pragma unroll
    for (int nt = 0; nt < 4; ++nt) {
#pragma unroll
        for (int kb = 0; kb < 2; ++kb)
#pragma unroll
            for (int j = 0; j < 8; ++j) {
                int k = kb * 32 + quad * 8 + j;
                bw[nt][kb][j] = (__bf16)st[4160 + k * 64 + nt * 16 + m];
            }
        b1v[nt] = st[8256 + nt * 16 + m];
        w2v[nt] = st[8320 + nt * 16 + m];
    }

    int wid = bid * 4 + (tid >> 6);
    int nW  = nblocks * 4;
    const int NT = N_USERS / 16;

    for (int tile = wid; tile < NT; tile += nW) {
        int row = tile * 16 + m;
        size_t base = (size_t)row * DIM;

        float hidf[2][8], dyf[2][8];
        if (cf) {
            const f32x4* cp = (const f32x4*)(cf + base);
            const f32x4* dp = (const f32x4*)(dy_buf + base);
#pragma unroll
            for (int kb = 0; kb < 2; ++kb) {
                f32x4 a = cp[kb * 8 + quad * 2], b = cp[kb * 8 + quad * 2 + 1];
                f32x4 c = dp[kb * 8 + quad * 2], d = dp[kb * 8 + quad * 2 + 1];
#pragma unroll
                for (int j = 0; j < 4; ++j) {
                    hidf[kb][j] = a[j]; hidf[kb][4 + j] = b[j];
                    dyf[kb][j]  = c[j]; dyf[kb][4 + j]  = d[j];
                }
            }
        } else {
#pragma unroll
            for (int kb = 0; kb < 2; ++kb)
#pragma unroll
                for (int j = 0; j < 8; ++j) {
                    int k = kb * 32 + quad * 8 + j;
                    hidf[kb][j] = __bfloat162float(cb[base + k]);
                    dyf[kb][j]  = dy_buf[base + k];
                }
        }

        bf16x8 ah[2], ad[2];
#pragma unroll
        for (int kb = 0; kb < 2; ++kb)
#pragma unroll
            for (int j = 0; j < 8; ++j) {
                ah[kb][j] = (__bf16)hidf[kb][j];
                ad[kb][j] = (__bf16)dyf[kb][j];
            }

        float zh[4] = {0.f, 0.f, 0.f, 0.f};
        float zd[4] = {0.f, 0.f, 0.f, 0.f};
#pragma unroll
        for (int nt = 0; nt < 4; ++nt) {
            f32x4 acch = {0.f, 0.f, 0.f, 0.f};
            f32x4 accd = {0.f, 0.f, 0.f, 0.f};
#pragma unroll
            for (int kb = 0; kb < 2; ++kb) {
                acch = __builtin_amdgcn_mfma_f32_16x16x32_bf16(ah[kb], bw[nt][kb], acch, 0, 0, 0);
                accd = __builtin_amdgcn_mfma_f32_16x16x32_bf16(ad[kb], bw[nt][kb], accd, 0, 0, 0);
            }
#pragma unroll
            for (int reg = 0; reg < 4; ++reg) {
                zh[reg] += tanhf(acch[reg] + b1v[nt]) * w2v[nt];
                zd[reg] += tanhf(accd[reg] + b1v[nt]) * w2v[nt];
            }
        }
        float s[4];
#pragma unroll
        for (int reg = 0; reg < 4; ++reg) {
#pragma unroll
            for (int off = 1; off < 16; off <<= 1) {
                zh[reg] += __shfl_xor(zh[reg], off, 64);
                zd[reg] += __shfl_xor(zd[reg], off, 64);
            }
            float mm = fmaxf(zh[reg], zd[reg]);
            float eh = expf(zh[reg] - mm), ed = expf(zd[reg] - mm);
            s[reg] = eh / (eh + ed);
        }
        int srcl = (m >> 2) * 16;
        float s0 = __shfl(s[0], srcl, 64), s1 = __shfl(s[1], srcl, 64);
        float s2 = __shfl(s[2], srcl, 64), s3 = __shfl(s[3], srcl, 64);
        int r3 = m & 3;
        float sv = (r3 == 0) ? s0 : (r3 == 1) ? s1 : (r3 == 2) ? s2 : s3;

        if (cf) {
            f32x4* cp = (f32x4*)(cf + base);
#pragma unroll
            for (int kb = 0; kb < 2; ++kb) {
                f32x4 v0, v1;
#pragma unroll
                for (int j = 0; j < 4; ++j) {
                    v0[j] = sv * hidf[kb][j]     + (1.f - sv) * dyf[kb][j];
                    v1[j] = sv * hidf[kb][4 + j] + (1.f - sv) * dyf[kb][4 + j];
                }
                cp[kb * 8 + quad * 2]     = v0;
                cp[kb * 8 + quad * 2 + 1] = v1;
                if (write_out && !f) {
#pragma unroll
                    for (int j = 0; j < 4; ++j) {
                        int k = kb * 32 + quad * 8 + j;
                        cb[base + k]     = __float2bfloat16(v0[j]);
                        cb[base + k + 4] = __float2bfloat16(v1[j]);
                    }
                }
            }
        } else {
#pragma unroll
            for (int kb = 0; kb < 2; ++kb)
#pragma unroll
                for (int j = 0; j < 8; ++j) {
                    int k = kb * 32 + quad * 8 + j;
                    float v = sv * hidf[kb][j] + (1.f - sv) * dyf[kb][j];
                    cb[base + k] = __float2bfloat16(v);
                }
        }
    }
}

// ---------------------------------------------------------------------------
// Kernel A: transform || build(0)   (proven in R8)
// ---------------------------------------------------------------------------
__global__ __launch_bounds__(256) void k_trans_build(
    const void* __restrict__ emb, const int* __restrict__ flag,
    const float* __restrict__ st, __hip_bfloat16* __restrict__ h,
    const int* __restrict__ nodes, const int* __restrict__ hyper,
    int* __restrict__ he, int* __restrict__ ne,
    int* __restrict__ hn, int* __restrict__ nn, int tag)
{
    __shared__ float Wl[DIM * DIM];
    __shared__ float bl[DIM];
    if ((int)blockIdx.x < TR_BLOCKS) {
        for (int i = threadIdx.x; i < DIM * DIM; i += blockDim.x) Wl[i] = st[i];
        if (threadIdx.x < DIM) bl[threadIdx.x] = st[4096 + threadIdx.x];
        __syncthreads();
        int f = *flag;
        int wave = threadIdx.x >> 6, lane = threadIdx.x & 63;
        int nW = TR_BLOCKS * 4;
        for (int row = blockIdx.x * 4 + wave; row < N_USERS; row += nW) {
            size_t base = (size_t)row * DIM;
            float v = ld_in(emb, base + lane, f);
            float acc = bl[lane];
#pragma unroll
            for (int k = 0; k < DIM; ++k)
                acc += __shfl(v, k, 64) * Wl[k * DIM + lane];
            h[base + lane] = __float2bfloat16(fmaxf(acc, 0.f));
        }
    } else {
        int i = (blockIdx.x - TR_BLOCKS) * blockDim.x + threadIdx.x;
        build_body(nodes, hyper, he, ne, hn, nn, tag, i);
    }
}

// ---------------------------------------------------------------------------
// Kernel B: gather_e — 16 chains/wave (R9: double MLP per wave; chain-walk
// is latency-bound, per-segment stall = E[max chain]/slots shrinks ~1.9x)
// ---------------------------------------------------------------------------
__global__ __launch_bounds__(256) void k_gather_e(
    const __hip_bfloat16* __restrict__ h,
    const int* __restrict__ nodes,
    const int* __restrict__ he, const int* __restrict__ ne,
    __hip_bfloat16* __restrict__ e, int tag)
{
    int lane = threadIdx.x & 63;
    int wid = blockIdx.x * (blockDim.x >> 6) + (threadIdx.x >> 6);
    int nW  = gridDim.x * (blockDim.x >> 6);
    for (int s0 = wid * 16; s0 < E_HYPER; s0 += nW * 16) {
        int idx[16]; float acc[16]; int cnt[16];
#pragma unroll
        for (int c = 0; c < 16; ++c) {
            int sg = s0 + c;
            idx[c] = (sg < E_HYPER) ? dec(he[sg], tag) : -1;
            acc[c] = 0.f; cnt[c] = 0;
        }
        while (true) {
            bool any = false;
#pragma unroll
            for (int c = 0; c < 16; ++c) any = any || (idx[c] >= 0);
            if (!any) break;
            int nxt[16], nd[16];
#pragma unroll
            for (int c = 0; c < 16; ++c)
                if (idx[c] >= 0) { nxt[c] = ne[idx[c]]; nd[c] = nodes[idx[c]]; }
#pragma unroll
            for (int c = 0; c < 16; ++c)
                if (idx[c] >= 0) {
                    acc[c] += __bfloat162float(h[(size_t)nd[c] * DIM + lane]);
                    cnt[c]++; idx[c] = dec(nxt[c], tag);
                }
        }
#pragma unroll
        for (int c = 0; c < 16; ++c) {
            int sg = s0 + c;
            if (sg < E_HYPER)
                e[(size_t)sg * DIM + lane] =
                    __float2bfloat16(acc[c] / (float)max(cnt[c], 1));
        }
    }
}

// ---------------------------------------------------------------------------
// Kernel C: gather_n — 16 chains/wave (R9), fp32 dy
// ---------------------------------------------------------------------------
__global__ __launch_bounds__(256) void k_gather_n(
    const __hip_bfloat16* __restrict__ e,
    const int* __restrict__ hyper,
    const int* __restrict__ hn, const int* __restrict__ nn,
    float* __restrict__ dy,
    void* __restrict__ out, float* __restrict__ cws,
    const int* __restrict__ flag, int use_ws, int to_carry, int tag)
{
    int f = *flag;
    int lane = threadIdx.x & 63;
    int wid = blockIdx.x * (blockDim.x >> 6) + (threadIdx.x >> 6);
    int nW  = gridDim.x * (blockDim.x >> 6);
    for (int s0 = wid * 16; s0 < N_USERS; s0 += nW * 16) {
        int idx[16]; float acc[16]; int cnt[16];
#pragma unroll
        for (int c = 0; c < 16; ++c) {
            int sg = s0 + c;
            idx[c] = (sg < N_USERS) ? dec(hn[sg], tag) : -1;
            acc[c] = 0.f; cnt[c] = 0;
        }
        while (true) {
            bool any = false;
#pragma unroll
            for (int c = 0; c < 16; ++c) any = any || (idx[c] >= 0);
            if (!any) break;
            int nxt[16], hy[16];
#pragma unroll
            for (int c = 0; c < 16; ++c)
                if (idx[c] >= 0) { nxt[c] = nn[idx[c]]; hy[c] = hyper[idx[c]]; }
#pragma unroll
            for (int c = 0; c < 16; ++c)
                if (idx[c] >= 0) {
                    acc[c] += __bfloat162float(e[(size_t)hy[c] * DIM + lane]);
                    cnt[c]++; idx[c] = dec(nxt[c], tag);
                }
        }
#pragma unroll
        for (int c = 0; c < 16; ++c) {
            int sg = s0 + c;
            if (sg < N_USERS) {
                float v = acc[c] / (float)max(cnt[c], 1);
                size_t o = (size_t)sg * DIM + lane;
                if (to_carry) st_carry(out, cws, o, f, use_ws, 0, v);
                else          dy[o] = v;
            }
        }
    }
}

// ---------------------------------------------------------------------------
// Kernel D: build(t+1) || fuse(t) — both cache-reuse-free (safe merge)
// ---------------------------------------------------------------------------
__global__ __launch_bounds__(256) void k_build_fuse(
    const int* __restrict__ nodes1, const int* __restrict__ hyper1,
    int* __restrict__ he, int* __restrict__ ne,
    int* __restrict__ hn, int* __restrict__ nn, int tag1, int nbuild,
    void* __restrict__ dout, float* __restrict__ cws,
    const float* __restrict__ dy_buf, const float* __restrict__ st,
    const int* __restrict__ flag, int use_ws, int do_fuse, int write_out)
{
    if ((int)blockIdx.x < nbuild) {
        int i = blockIdx.x * blockDim.x + threadIdx.x;
        build_body(nodes1, hyper1, he, ne, hn, nn, tag1, i);
    } else if (do_fuse) {
        fu_body(dout, cws, dy_buf, st, *flag, use_ws, write_out,
                blockIdx.x - nbuild, gridDim.x - nbuild, threadIdx.x);
    }
}

// ---------------------------------------------------------------------------
extern "C" void kernel_launch(void* const* d_in, const int* in_sizes, int n_in,
                              void* d_out, int out_size, void* d_ws,
                              size_t ws_size, hipStream_t stream)
{
    const void* user_emb = d_in[0];
    const void* W_conv   = d_in[1];
    const void* b_conv   = d_in[2];
    const void* fus_w1   = d_in[3];
    const void* fus_b1   = d_in[4];
    const void* fus_w2   = d_in[5];
    const void* fus_b2   = d_in[6];
    const int* edge_nodes = (const int*)d_in[7];
    const int* edge_hyper = (const int*)d_in[8];

    const size_t ND = (size_t)N_USERS * DIM;

    // ws layout (fp32 word offsets) — R7-proven base (51.83 MB):
    //   0        : flag
    //   16       : st [8448]
    //   8464     : head_e int [50000]
    //   58464    : head_n int [100000]
    //   158464   : next_e int [800000]
    //   958464   : next_n int [800000]
    //   1758464  : e bf16 [E*D]
    //   3358464  : dy fp32 [N*D]
    //   9758464  : h bf16 [N*D]
    //   12958464 : optional fp32 carry [N*D] -> 77.43 MB
    float* ws = (float*)d_ws;
    int*   flag   = (int*)ws;
    float* st     = ws + 16;
    int*   head_e = (int*)(ws + 8464);
    int*   head_n = (int*)(ws + 58464);
    int*   next_e = (int*)(ws + 158464);
    int*   next_n = (int*)(ws + 958464);
    __hip_bfloat16* e_buf = (__hip_bfloat16*)(ws + 1758464);
    float* dy_buf = ws + 3358464;
    __hip_bfloat16* h = (__hip_bfloat16*)(ws + 9758464);
    float* carry_ws   = ws + 12958464;

    const size_t need_ws_carry = (12958464 + ND) * 4;
    const int use_ws = (ws_size >= need_ws_carry) ? 1 : 0;

    k_detect<<<1, 256, 0, stream>>>((const unsigned short*)user_emb, flag);
    k_convert_params<<<(8385 + 255) / 256, 256, 0, stream>>>(
        W_conv, b_conv, fus_w1, fus_b1, fus_w2, fus_b2, flag, st);

    // prologue: transform || build(0)  (tag 1)
    k_trans_build<<<TR_BLOCKS + B_BLOCKS, 256, 0, stream>>>(
        user_emb, flag, st, h, edge_nodes, edge_hyper,
        head_e, next_e, head_n, next_n, 1);

    for (int t = 0; t < T_STEPS; ++t) {
        const int* nodes  = edge_nodes + (size_t)t * NNZ_E;
        const int* hyper  = edge_hyper + (size_t)t * NNZ_E;
        const int* nodes1 = edge_nodes + (size_t)(t + 1) * NNZ_E;
        const int* hyper1 = edge_hyper + (size_t)(t + 1) * NNZ_E;
        int tag = t + 1;

        k_gather_e<<<GE_BLOCKS, 256, 0, stream>>>(
            h, nodes, head_e, next_e, e_buf, tag);
        k_gather_n<<<GN_BLOCKS, 256, 0, stream>>>(
            e_buf, hyper, head_n, next_n, dy_buf,
            d_out, carry_ws, flag, use_ws, (t == 0) ? 1 : 0, tag);

        // build(t+1) || fuse(t)   (t=0: build only; t=7: fuse only)
        int do_b  = (t < T_STEPS - 1) ? 1 : 0;
        int do_f  = (t > 0) ? 1 : 0;
        int nb    = do_b ? B_BLOCKS : 0;
        int grid  = nb + (do_f ? FU_BLOCKS : 0);
        k_build_fuse<<<grid, 256, 0, stream>>>(
            do_b ? nodes1 : nodes, do_b ? hyper1 : hyper,
            head_e, next_e, head_n, next_n, t + 2, nb,
            d_out, carry_ws, dy_buf, st, flag, use_ws, do_f,
            (t == T_STEPS - 1) ? 1 : 0);
    }
}

// Round 2
// 2935.350 us; speedup vs baseline: 1.2553x; 1.2553x over previous
//
#include <hip/hip_runtime.h>
#include <hip/hip_bf16.h>

#define N_USERS 100000
#define E_HYPER 50000
#define NNZ_E   800000
#define T_STEPS 8
#define DIM     64

#define TR_BLOCKS 1024
#define GE_BLOCKS 1563
#define GN_BLOCKS 3125
#define HS_BLOCKS 3125
#define FU_BLOCKS 1024

#define SCAN_EBLKS 49     // ceil(50000/1024)
#define SCAN_NBLKS 98     // ceil(100000/1024)
#define SCAN_BLKS  147
#define ZERO_BLKS  147    // 147*256 int4 = 150528 ints >= 150000

typedef __bf16 bf16x8 __attribute__((ext_vector_type(8)));
typedef float  f32x4  __attribute__((ext_vector_type(4)));

// ---------------------------------------------------------------------------
__device__ __forceinline__ float ld_in(const void* p, size_t i, int f32)
{
    return f32 ? ((const float*)p)[i]
               : __bfloat162float(((const __hip_bfloat16*)p)[i]);
}

// carry store: f32-in-dout(f=1) | f32-in-ws | bf16-in-dout
__device__ __forceinline__ void st_carry(void* out, float* cws, size_t i,
                                         int f, int use_ws, float v)
{
    if (f) { ((float*)out)[i] = v; return; }
    if (use_ws) { cws[i] = v; return; }
    ((__hip_bfloat16*)out)[i] = __float2bfloat16(v);
}

// ---------------------------------------------------------------------------
// Kernel 0: input dtype detector (proven: resolves f=0 for bf16 inputs)
// ---------------------------------------------------------------------------
__global__ void k_detect(const unsigned short* __restrict__ raw, int* __restrict__ flag)
{
    __shared__ int cnt;
    if (threadIdx.x == 0) cnt = 0;
    __syncthreads();
    int c = 0;
    for (int i = threadIdx.x; i < 4096; i += blockDim.x) {
        int e = (raw[i] >> 7) & 0xFF;
        if (e > 126) c++;
    }
    atomicAdd(&cnt, c);
    __syncthreads();
    if (threadIdx.x == 0) *flag = (cnt > 64) ? 1 : 0;
}

// ---------------------------------------------------------------------------
// Kernel 0b: params -> fp32 staging
// st: W[0,4096) b[4096,4160) w1[4160,8256) b1[8256,8320) w2[8320,8384) b2[8384]
// ---------------------------------------------------------------------------
__global__ void k_convert_params(
    const void* W, const void* b, const void* w1, const void* b1,
    const void* w2, const void* b2, const int* __restrict__ flag,
    float* __restrict__ st)
{
    int f = *flag;
    int i = blockIdx.x * blockDim.x + threadIdx.x;
    if (i < 4096)          st[i] = ld_in(W,  i,        f);
    else if (i < 4160)     st[i] = ld_in(b,  i - 4096, f);
    else if (i < 8256)     st[i] = ld_in(w1, i - 4160, f);
    else if (i < 8320)     st[i] = ld_in(b1, i - 8256, f);
    else if (i < 8384)     st[i] = ld_in(w2, i - 8320, f);
    else if (i == 8384)    st[i] = ld_in(b2, 0,        f);
}

// ---------------------------------------------------------------------------
// CSR build stage 1: histogram into off arrays (must be zeroed first)
// ---------------------------------------------------------------------------
__device__ __forceinline__ void hist_body(
    const int* __restrict__ nodes, const int* __restrict__ hyper,
    int* __restrict__ off_e, int* __restrict__ off_n, int i)
{
    if (i >= NNZ_E) return;
    atomicAdd(&off_e[hyper[i]], 1);
    atomicAdd(&off_n[nodes[i]], 1);
}

__global__ __launch_bounds__(256) void k_hist(
    const int* __restrict__ nodes, const int* __restrict__ hyper,
    int* __restrict__ off_e, int* __restrict__ off_n)
{
    hist_body(nodes, hyper, off_e, off_n,
              blockIdx.x * blockDim.x + threadIdx.x);
}

// ---------------------------------------------------------------------------
// CSR build stage 2a: per-block exclusive scan (1024 elems/block) + block sums
// blocks [0,49) -> off_e (50000), blocks [49,147) -> off_n (100000)
// ---------------------------------------------------------------------------
__global__ __launch_bounds__(256) void k_scan1(
    int* __restrict__ off_e, int* __restrict__ off_n, int* __restrict__ bsum)
{
    int b = blockIdx.x;
    int* arr; int n; int base;
    if (b < SCAN_EBLKS) { arr = off_e; n = E_HYPER; base = b * 1024; }
    else                { arr = off_n; n = N_USERS; base = (b - SCAN_EBLKS) * 1024; }

    int tid  = threadIdx.x;
    int lane = tid & 63, wv = tid >> 6;
    int i0 = base + tid * 4;

    int v[4];
#pragma unroll
    for (int j = 0; j < 4; ++j) {
        int i = i0 + j;
        v[j] = (i < n) ? arr[i] : 0;
    }
    int s4 = v[0] + v[1] + v[2] + v[3];

    // inclusive scan of s4 across wave
    int inc = s4;
#pragma unroll
    for (int off = 1; off < 64; off <<= 1) {
        int o = __shfl_up(inc, off, 64);
        if (lane >= off) inc += o;
    }
    __shared__ int wsum[4];
    if (lane == 63) wsum[wv] = inc;
    __syncthreads();
    int wpre = 0;
#pragma unroll
    for (int w = 0; w < 4; ++w) if (w < wv) wpre += wsum[w];

    int run = wpre + inc - s4;   // exclusive prefix of this thread's 4-group
#pragma unroll
    for (int j = 0; j < 4; ++j) {
        int i = i0 + j;
        if (i < n) arr[i] = run;
        run += v[j];
    }
    if (tid == 255) bsum[b] = wpre + inc;   // block total
}

// ---------------------------------------------------------------------------
// CSR build stage 2b: add prefix of block sums (same block mapping as scan1)
// ---------------------------------------------------------------------------
__global__ __launch_bounds__(256) void k_scan_fix(
    int* __restrict__ off_e, int* __restrict__ off_n,
    const int* __restrict__ bsum)
{
    int b = blockIdx.x;
    int* arr; int n; int base; int lo;
    if (b < SCAN_EBLKS) { arr = off_e; n = E_HYPER; base = b * 1024; lo = 0; }
    else { arr = off_n; n = N_USERS; base = (b - SCAN_EBLKS) * 1024; lo = SCAN_EBLKS; }

    int tid = threadIdx.x;
    int j = lo + tid;
    int contrib = (j < b) ? bsum[j] : 0;   // b - lo <= 97 < 256
#pragma unroll
    for (int off = 1; off < 64; off <<= 1)
        contrib += __shfl_xor(contrib, off, 64);
    __shared__ int ws[4];
    if ((tid & 63) == 0) ws[tid >> 6] = contrib;
    __syncthreads();
    int P = ws[0] + ws[1] + ws[2] + ws[3];

    int i0 = base + tid * 4;
#pragma unroll
    for (int k = 0; k < 4; ++k) {
        int i = i0 + k;
        if (i < n) arr[i] += P;
    }
}

// ---------------------------------------------------------------------------
// CSR build stage 3: scatter. Bumps off[] in place; post-scatter off[s] is the
// INCLUSIVE end of segment s (start(s) = s==0 ? 0 : off[s-1]).
// ---------------------------------------------------------------------------
__global__ __launch_bounds__(256) void k_scatter(
    const int* __restrict__ nodes, const int* __restrict__ hyper,
    int* __restrict__ off_e, int* __restrict__ off_n,
    int* __restrict__ sn, int* __restrict__ sh)
{
    int i = blockIdx.x * blockDim.x + threadIdx.x;
    if (i >= NNZ_E) return;
    int nd = nodes[i], hy = hyper[i];
    int p = atomicAdd(&off_e[hy], 1); sn[p] = nd;
    int q = atomicAdd(&off_n[nd], 1); sh[q] = hy;
}

// ---------------------------------------------------------------------------
// fuse body: carry = softmax-blend(carry, dy) via MFMA 16x16x32 bf16
// (R5/R7-proven fragment layout; b2 cancels in 2-way softmax)
// ---------------------------------------------------------------------------
__device__ __forceinline__ void fu_body(
    void* __restrict__ dout, float* __restrict__ cws,
    const float* __restrict__ dy_buf, const float* __restrict__ st,
    int f, int use_ws, int write_out, int bid, int nblocks, int tid)
{
    float* cf = f ? (float*)dout : (use_ws ? cws : (float*)0);
    __hip_bfloat16* cb = (__hip_bfloat16*)dout;

    int lane = tid & 63;
    int quad = lane >> 4;
    int m    = lane & 15;

    bf16x8 bw[4][2];
    float b1v[4], w2v[4];
#pragma unroll
    for (int nt = 0; nt < 4; ++nt) {
#pragma unroll
        for (int kb = 0; kb < 2; ++kb)
#pragma unroll
            for (int j = 0; j < 8; ++j) {
                int k = kb * 32 + quad * 8 + j;
                bw[nt][kb][j] = (__bf16)st[4160 + k * 64 + nt * 16 + m];
            }
        b1v[nt] = st[8256 + nt * 16 + m];
        w2v[nt] = st[8320 + nt * 16 + m];
    }

    int wid = bid * 4 + (tid >> 6);
    int nW  = nblocks * 4;
    const int NT = N_USERS / 16;

    for (int tile = wid; tile < NT; tile += nW) {
        int row = tile * 16 + m;
        size_t base = (size_t)row * DIM;

        float hidf[2][8], dyf[2][8];
        if (cf) {
            const f32x4* cp = (const f32x4*)(cf + base);
            const f32x4* dp = (const f32x4*)(dy_buf + base);
#pragma unroll
            for (int kb = 0; kb < 2; ++kb) {
                f32x4 a = cp[kb * 8 + quad * 2], b = cp[kb * 8 + quad * 2 + 1];
                f32x4 c = dp[kb * 8 + quad * 2], d = dp[kb * 8 + quad * 2 + 1];
#pragma unroll
                for (int j = 0; j < 4; ++j) {
                    hidf[kb][j] = a[j]; hidf[kb][4 + j] = b[j];
                    dyf[kb][j]  = c[j]; dyf[kb][4 + j]  = d[j];
                }
            }
        } else {
#pragma unroll
            for (int kb = 0; kb < 2; ++kb)
#pragma unroll
                for (int j = 0; j < 8; ++j) {
                    int k = kb * 32 + quad * 8 + j;
                    hidf[kb][j] = __bfloat162float(cb[base + k]);
                    dyf[kb][j]  = dy_buf[base + k];
                }
        }

        bf16x8 ah[2], ad[2];
#pragma unroll
        for (int kb = 0; kb < 2; ++kb)
#pragma unroll
            for (int j = 0; j < 8; ++j) {
                ah[kb][j] = (__bf16)hidf[kb][j];
                ad[kb][j] = (__bf16)dyf[kb][j];
            }

        float zh[4] = {0.f, 0.f, 0.f, 0.f};
        float zd[4] = {0.f, 0.f, 0.f, 0.f};
#pragma unroll
        for (int nt = 0; nt < 4; ++nt) {
            f32x4 acch = {0.f, 0.f, 0.f, 0.f};
            f32x4 accd = {0.f, 0.f, 0.f, 0.f};
#pragma unroll
            for (int kb = 0; kb < 2; ++kb) {
                acch = __builtin_amdgcn_mfma_f32_16x16x32_bf16(ah[kb], bw[nt][kb], acch, 0, 0, 0);
                accd = __builtin_amdgcn_mfma_f32_16x16x32_bf16(ad[kb], bw[nt][kb], accd, 0, 0, 0);
            }
#pragma unroll
            for (int reg = 0; reg < 4; ++reg) {
                zh[reg] += tanhf(acch[reg] + b1v[nt]) * w2v[nt];
                zd[reg] += tanhf(accd[reg] + b1v[nt]) * w2v[nt];
            }
        }
        float s[4];
#pragma unroll
        for (int reg = 0; reg < 4; ++reg) {
#pragma unroll
            for (int off = 1; off < 16; off <<= 1) {
                zh[reg] += __shfl_xor(zh[reg], off, 64);
                zd[reg] += __shfl_xor(zd[reg], off, 64);
            }
            float mm = fmaxf(zh[reg], zd[reg]);
            float eh = expf(zh[reg] - mm), ed = expf(zd[reg] - mm);
            s[reg] = eh / (eh + ed);
        }
        int srcl = (m >> 2) * 16;
        float s0 = __shfl(s[0], srcl, 64), s1 = __shfl(s[1], srcl, 64);
        float s2 = __shfl(s[2], srcl, 64), s3 = __shfl(s[3], srcl, 64);
        int r3 = m & 3;
        float sv = (r3 == 0) ? s0 : (r3 == 1) ? s1 : (r3 == 2) ? s2 : s3;

        if (cf) {
            f32x4* cp = (f32x4*)(cf + base);
#pragma unroll
            for (int kb = 0; kb < 2; ++kb) {
                f32x4 v0, v1;
#pragma unroll
                for (int j = 0; j < 4; ++j) {
                    v0[j] = sv * hidf[kb][j]     + (1.f - sv) * dyf[kb][j];
                    v1[j] = sv * hidf[kb][4 + j] + (1.f - sv) * dyf[kb][4 + j];
                }
                cp[kb * 8 + quad * 2]     = v0;
                cp[kb * 8 + quad * 2 + 1] = v1;
                if (write_out && !f) {
#pragma unroll
                    for (int j = 0; j < 4; ++j) {
                        int k = kb * 32 + quad * 8 + j;
                        cb[base + k]     = __float2bfloat16(v0[j]);
                        cb[base + k + 4] = __float2bfloat16(v1[j]);
                    }
                }
            }
        } else {
#pragma unroll
            for (int kb = 0; kb < 2; ++kb)
#pragma unroll
                for (int j = 0; j < 8; ++j) {
                    int k = kb * 32 + quad * 8 + j;
                    float v = sv * hidf[kb][j] + (1.f - sv) * dyf[kb][j];
                    cb[base + k] = __float2bfloat16(v);
                }
        }
    }
}

// ---------------------------------------------------------------------------
// Kernel A: transform || hist(0)
// ---------------------------------------------------------------------------
__global__ __launch_bounds__(256) void k_trans_hist(
    const void* __restrict__ emb, const int* __restrict__ flag,
    const float* __restrict__ st, __hip_bfloat16* __restrict__ h,
    const int* __restrict__ nodes, const int* __restrict__ hyper,
    int* __restrict__ off_e, int* __restrict__ off_n)
{
    __shared__ float Wl[DIM * DIM];
    __shared__ float bl[DIM];
    if ((int)blockIdx.x < TR_BLOCKS) {
        for (int i = threadIdx.x; i < DIM * DIM; i += blockDim.x) Wl[i] = st[i];
        if (threadIdx.x < DIM) bl[threadIdx.x] = st[4096 + threadIdx.x];
        __syncthreads();
        int f = *flag;
        int wave = threadIdx.x >> 6, lane = threadIdx.x & 63;
        int nW = TR_BLOCKS * 4;
        for (int row = blockIdx.x * 4 + wave; row < N_USERS; row += nW) {
            size_t base = (size_t)row * DIM;
            float v = ld_in(emb, base + lane, f);
            float acc = bl[lane];
#pragma unroll
            for (int k = 0; k < DIM; ++k)
                acc += __shfl(v, k, 64) * Wl[k * DIM + lane];
            h[base + lane] = __float2bfloat16(fmaxf(acc, 0.f));
        }
    } else {
        int i = (blockIdx.x - TR_BLOCKS) * blockDim.x + threadIdx.x;
        hist_body(nodes, hyper, off_e, off_n, i);
    }
}

// ---------------------------------------------------------------------------
// Kernel B: gather_e — CSR ranges, 8 segments/wave, no dependent chain
// ---------------------------------------------------------------------------
__global__ __launch_bounds__(256) void k_gather_e(
    const __hip_bfloat16* __restrict__ h,
    const int* __restrict__ sn, const int* __restrict__ off_e,
    __hip_bfloat16* __restrict__ e)
{
    int lane = threadIdx.x & 63;
    int wid = blockIdx.x * (blockDim.x >> 6) + (threadIdx.x >> 6);
    int nW  = gridDim.x * (blockDim.x >> 6);
    for (int s0 = wid * 8; s0 < E_HYPER; s0 += nW * 8) {
        int pos[8], end8[8], cnt8[8]; float acc[8];
#pragma unroll
        for (int c = 0; c < 8; ++c) {
            int sg = s0 + c;
            if (sg < E_HYPER) {
                pos[c]  = (sg == 0) ? 0 : off_e[sg - 1];
                end8[c] = off_e[sg];
            } else { pos[c] = 0; end8[c] = 0; }
            cnt8[c] = end8[c] - pos[c];
            acc[c] = 0.f;
        }
        while (true) {
            bool any = false;
#pragma unroll
            for (int c = 0; c < 8; ++c) any = any || (pos[c] < end8[c]);
            if (!any) break;
            int id[8];
#pragma unroll
            for (int c = 0; c < 8; ++c)
                if (pos[c] < end8[c]) id[c] = sn[pos[c]];
#pragma unroll
            for (int c = 0; c < 8; ++c)
                if (pos[c] < end8[c]) {
                    acc[c] += __bfloat162float(h[(size_t)id[c] * DIM + lane]);
                    pos[c]++;
                }
        }
#pragma unroll
        for (int c = 0; c < 8; ++c) {
            int sg = s0 + c;
            if (sg < E_HYPER)
                e[(size_t)sg * DIM + lane] =
                    __float2bfloat16(acc[c] / (float)max(cnt8[c], 1));
        }
    }
}

// ---------------------------------------------------------------------------
// Kernel C: gather_n — CSR ranges, 8 segments/wave, fp32 dy
// ---------------------------------------------------------------------------
__global__ __launch_bounds__(256) void k_gather_n(
    const __hip_bfloat16* __restrict__ e,
    const int* __restrict__ sh, const int* __restrict__ off_n,
    float* __restrict__ dy,
    void* __restrict__ out, float* __restrict__ cws,
    const int* __restrict__ flag, int use_ws, int to_carry)
{
    int f = *flag;
    int lane = threadIdx.x & 63;
    int wid = blockIdx.x * (blockDim.x >> 6) + (threadIdx.x >> 6);
    int nW  = gridDim.x * (blockDim.x >> 6);
    for (int s0 = wid * 8; s0 < N_USERS; s0 += nW * 8) {
        int pos[8], end8[8], cnt8[8]; float acc[8];
#pragma unroll
        for (int c = 0; c < 8; ++c) {
            int sg = s0 + c;
            if (sg < N_USERS) {
                pos[c]  = (sg == 0) ? 0 : off_n[sg - 1];
                end8[c] = off_n[sg];
            } else { pos[c] = 0; end8[c] = 0; }
            cnt8[c] = end8[c] - pos[c];
            acc[c] = 0.f;
        }
        while (true) {
            bool any = false;
#pragma unroll
            for (int c = 0; c < 8; ++c) any = any || (pos[c] < end8[c]);
            if (!any) break;
            int hy[8];
#pragma unroll
            for (int c = 0; c < 8; ++c)
                if (pos[c] < end8[c]) hy[c] = sh[pos[c]];
#pragma unroll
            for (int c = 0; c < 8; ++c)
                if (pos[c] < end8[c]) {
                    acc[c] += __bfloat162float(e[(size_t)hy[c] * DIM + lane]);
                    pos[c]++;
                }
        }
#pragma unroll
        for (int c = 0; c < 8; ++c) {
            int sg = s0 + c;
            if (sg < N_USERS) {
                float v = acc[c] / (float)max(cnt8[c], 1);
                size_t o = (size_t)sg * DIM + lane;
                if (to_carry) st_carry(out, cws, o, f, use_ws, v);
                else          dy[o] = v;
            }
        }
    }
}

// ---------------------------------------------------------------------------
// Kernel D: zero(off arrays for next build) || fuse(t)
// zero blocks: 147 x 256 threads x int4 = 150528 ints covers off_e+off_n
// (off_e and off_n are contiguous in ws)
// ---------------------------------------------------------------------------
__global__ __launch_bounds__(256) void k_fuse_zero(
    int* __restrict__ zbase, int nzero, int do_zero,
    void* __restrict__ dout, float* __restrict__ cws,
    const float* __restrict__ dy_buf, const float* __restrict__ st,
    const int* __restrict__ flag, int use_ws, int do_fuse, int write_out)
{
    if ((int)blockIdx.x < nzero) {
        if (do_zero) {
            int idx = blockIdx.x * 256 + threadIdx.x;
            if (idx < (E_HYPER + N_USERS) / 4)
                ((int4*)zbase)[idx] = make_int4(0, 0, 0, 0);
        }
    } else if (do_fuse) {
        fu_body(dout, cws, dy_buf, st, *flag, use_ws, write_out,
                blockIdx.x - nzero, gridDim.x - nzero, threadIdx.x);
    }
}

// ---------------------------------------------------------------------------
extern "C" void kernel_launch(void* const* d_in, const int* in_sizes, int n_in,
                              void* d_out, int out_size, void* d_ws,
                              size_t ws_size, hipStream_t stream)
{
    const void* user_emb = d_in[0];
    const void* W_conv   = d_in[1];
    const void* b_conv   = d_in[2];
    const void* fus_w1   = d_in[3];
    const void* fus_b1   = d_in[4];
    const void* fus_w2   = d_in[5];
    const void* fus_b2   = d_in[6];
    const int* edge_nodes = (const int*)d_in[7];
    const int* edge_hyper = (const int*)d_in[8];

    const size_t ND = (size_t)N_USERS * DIM;

    // ws layout (fp32 word offsets) — same 77.43 MB max footprint as R0:
    //   0        : flag
    //   16       : st [8448]
    //   8464     : off_e int [50000]   (contiguous with off_n for zeroing)
    //   58464    : off_n int [100000]
    //   158464   : sn int [800000]  (nodes sorted by hyperedge)
    //   958464   : sh int [800000]  (hyperedges sorted by node)
    //   1758464  : e bf16 [E*D]
    //   3358464  : dy fp32 [N*D]    (first 512 words alias scan bsum — dy is
    //                                dead at scan time: consumed by fuse)
    //   9758464  : h bf16 [N*D]
    //   12958464 : optional fp32 carry [N*D] -> 77.43 MB
    float* ws = (float*)d_ws;
    int*   flag   = (int*)ws;
    float* st     = ws + 16;
    int*   off_e  = (int*)(ws + 8464);
    int*   off_n  = (int*)(ws + 58464);
    int*   sn     = (int*)(ws + 158464);
    int*   sh     = (int*)(ws + 958464);
    __hip_bfloat16* e_buf = (__hip_bfloat16*)(ws + 1758464);
    float* dy_buf = ws + 3358464;
    int*   bsum   = (int*)(ws + 3358464);   // alias: dy dead during scans
    __hip_bfloat16* h = (__hip_bfloat16*)(ws + 9758464);
    float* carry_ws   = ws + 12958464;

    const size_t need_ws_carry = (12958464 + ND) * 4;
    const int use_ws = (ws_size >= need_ws_carry) ? 1 : 0;

    k_detect<<<1, 256, 0, stream>>>((const unsigned short*)user_emb, flag);
    k_convert_params<<<(8385 + 255) / 256, 256, 0, stream>>>(
        W_conv, b_conv, fus_w1, fus_b1, fus_w2, fus_b2, flag, st);

    // prologue: zero, transform || hist(0), scan, scatter(0)
    k_fuse_zero<<<ZERO_BLKS, 256, 0, stream>>>(
        off_e, ZERO_BLKS, 1, d_out, carry_ws, dy_buf, st, flag, use_ws, 0, 0);
    k_trans_hist<<<TR_BLOCKS + HS_BLOCKS, 256, 0, stream>>>(
        user_emb, flag, st, h, edge_nodes, edge_hyper, off_e, off_n);
    k_scan1<<<SCAN_BLKS, 256, 0, stream>>>(off_e, off_n, bsum);
    k_scan_fix<<<SCAN_BLKS, 256, 0, stream>>>(off_e, off_n, bsum);
    k_scatter<<<HS_BLOCKS, 256, 0, stream>>>(
        edge_nodes, edge_hyper, off_e, off_n, sn, sh);

    for (int t = 0; t < T_STEPS; ++t) {
        const int* nodes1 = edge_nodes + (size_t)(t + 1) * NNZ_E;
        const int* hyper1 = edge_hyper + (size_t)(t + 1) * NNZ_E;

        k_gather_e<<<GE_BLOCKS, 256, 0, stream>>>(h, sn, off_e, e_buf);
        k_gather_n<<<GN_BLOCKS, 256, 0, stream>>>(
            e_buf, sh, off_n, dy_buf,
            d_out, carry_ws, flag, use_ws, (t == 0) ? 1 : 0);

        // zero(next-build offsets) || fuse(t)
        int do_b = (t < T_STEPS - 1) ? 1 : 0;
        int do_f = (t > 0) ? 1 : 0;
        int nz   = do_b ? ZERO_BLKS : 0;
        int grid = nz + (do_f ? FU_BLOCKS : 0);
        if (grid > 0)
            k_fuse_zero<<<grid, 256, 0, stream>>>(
                off_e, nz, do_b, d_out, carry_ws, dy_buf, st, flag, use_ws,
                do_f, (t == T_STEPS - 1) ? 1 : 0);

        if (do_b) {
            k_hist<<<HS_BLOCKS, 256, 0, stream>>>(nodes1, hyper1, off_e, off_n);
            k_scan1<<<SCAN_BLKS, 256, 0, stream>>>(off_e, off_n, bsum);
            k_scan_fix<<<SCAN_BLKS, 256, 0, stream>>>(off_e, off_n, bsum);
            k_scatter<<<HS_BLOCKS, 256, 0, stream>>>(
                nodes1, hyper1, off_e, off_n, sn, sh);
        }
    }
}

// Round 3
// 2377.565 us; speedup vs baseline: 1.5498x; 1.2346x over previous
//
#include <hip/hip_runtime.h>
#include <hip/hip_bf16.h>

#define N_USERS 100000
#define E_HYPER 50000
#define NNZ_E   800000
#define T_STEPS 8
#define DIM     64

#define TR_BLOCKS 1024
#define GE_BLOCKS 1563
#define GN_BLOCKS 3125
#define HS_BLOCKS 3125
#define FU_BLOCKS 1024

#define SCAN_EBLKS 49     // ceil(50000/1024)
#define SCAN_BLKS  147    // 49 + 98
#define ZERO_BLKS  147    // 147*256 int4 = 37632 >= 37500 (one off buffer)
#define ZALL_BLKS  294    // both off buffers: 75000 int4

#define SC_PARTS   8
#define SC_SUB     256    // blocks per partition
#define SC_BLOCKS  (SC_PARTS * SC_SUB)   // 2048
#define SC_CHUNK   (NNZ_E / SC_SUB)      // 3125
#define E_SLICE    (E_HYPER / SC_PARTS)  // 6250
#define N_SLICE    (N_USERS / SC_PARTS)  // 12500

typedef __bf16 bf16x8 __attribute__((ext_vector_type(8)));
typedef float  f32x4  __attribute__((ext_vector_type(4)));

// ---------------------------------------------------------------------------
__device__ __forceinline__ float ld_in(const void* p, size_t i, int f32)
{
    return f32 ? ((const float*)p)[i]
               : __bfloat162float(((const __hip_bfloat16*)p)[i]);
}

// carry store: f32-in-dout(f=1) | f32-in-ws | bf16-in-dout
__device__ __forceinline__ void st_carry(void* out, float* cws, size_t i,
                                         int f, int use_ws, float v)
{
    if (f) { ((float*)out)[i] = v; return; }
    if (use_ws) { cws[i] = v; return; }
    ((__hip_bfloat16*)out)[i] = __float2bfloat16(v);
}

// ---------------------------------------------------------------------------
// Kernel 0: input dtype detector
// ---------------------------------------------------------------------------
__global__ void k_detect(const unsigned short* __restrict__ raw, int* __restrict__ flag)
{
    __shared__ int cnt;
    if (threadIdx.x == 0) cnt = 0;
    __syncthreads();
    int c = 0;
    for (int i = threadIdx.x; i < 4096; i += blockDim.x) {
        int e = (raw[i] >> 7) & 0xFF;
        if (e > 126) c++;
    }
    atomicAdd(&cnt, c);
    __syncthreads();
    if (threadIdx.x == 0) *flag = (cnt > 64) ? 1 : 0;
}

// ---------------------------------------------------------------------------
// Kernel 0b: params -> fp32 staging
// st: W[0,4096) b[4096,4160) w1[4160,8256) b1[8256,8320) w2[8320,8384) b2[8384]
// ---------------------------------------------------------------------------
__global__ void k_convert_params(
    const void* W, const void* b, const void* w1, const void* b1,
    const void* w2, const void* b2, const int* __restrict__ flag,
    float* __restrict__ st)
{
    int f = *flag;
    int i = blockIdx.x * blockDim.x + threadIdx.x;
    if (i < 4096)          st[i] = ld_in(W,  i,        f);
    else if (i < 4160)     st[i] = ld_in(b,  i - 4096, f);
    else if (i < 8256)     st[i] = ld_in(w1, i - 4160, f);
    else if (i < 8320)     st[i] = ld_in(b1, i - 8256, f);
    else if (i < 8384)     st[i] = ld_in(w2, i - 8320, f);
    else if (i == 8384)    st[i] = ld_in(b2, 0,        f);
}

// ---------------------------------------------------------------------------
// bodies: hist / scan1 / scan_fix / scatter(XCD-partitioned) / zero
// off layout: off[0..E_HYPER) = per-hyperedge, off[E_HYPER..E_HYPER+N_USERS) = per-node
// ---------------------------------------------------------------------------
__device__ __forceinline__ void hist_body(
    const int* __restrict__ nodes, const int* __restrict__ hyper,
    int* __restrict__ off, int i)
{
    if (i >= NNZ_E) return;
    atomicAdd(&off[hyper[i]], 1);
    atomicAdd(&off[E_HYPER + nodes[i]], 1);
}

__device__ __forceinline__ void scan1_body(
    int* __restrict__ off, int* __restrict__ bsum, int b, int tid)
{
    int* arr; int n; int base;
    if (b < SCAN_EBLKS) { arr = off; n = E_HYPER; base = b * 1024; }
    else { arr = off + E_HYPER; n = N_USERS; base = (b - SCAN_EBLKS) * 1024; }

    int lane = tid & 63, wv = tid >> 6;
    int i0 = base + tid * 4;

    int v[4];
#pragma unroll
    for (int j = 0; j < 4; ++j) {
        int i = i0 + j;
        v[j] = (i < n) ? arr[i] : 0;
    }
    int s4 = v[0] + v[1] + v[2] + v[3];

    int inc = s4;
#pragma unroll
    for (int off_ = 1; off_ < 64; off_ <<= 1) {
        int o = __shfl_up(inc, off_, 64);
        if (lane >= off_) inc += o;
    }
    __shared__ int wsum[4];
    if (lane == 63) wsum[wv] = inc;
    __syncthreads();
    int wpre = 0;
#pragma unroll
    for (int w = 0; w < 4; ++w) if (w < wv) wpre += wsum[w];

    int run = wpre + inc - s4;
#pragma unroll
    for (int j = 0; j < 4; ++j) {
        int i = i0 + j;
        if (i < n) arr[i] = run;
        run += v[j];
    }
    if (tid == 255) bsum[b] = wpre + inc;
}

__device__ __forceinline__ void fix_body(
    int* __restrict__ off, const int* __restrict__ bsum, int b, int tid)
{
    int* arr; int n; int base; int lo;
    if (b < SCAN_EBLKS) { arr = off; n = E_HYPER; base = b * 1024; lo = 0; }
    else { arr = off + E_HYPER; n = N_USERS; base = (b - SCAN_EBLKS) * 1024; lo = SCAN_EBLKS; }

    int j = lo + tid;
    int contrib = (j < b) ? bsum[j] : 0;
#pragma unroll
    for (int off_ = 1; off_ < 64; off_ <<= 1)
        contrib += __shfl_xor(contrib, off_, 64);
    __shared__ int wsf[4];
    if ((tid & 63) == 0) wsf[tid >> 6] = contrib;
    __syncthreads();
    int P = wsf[0] + wsf[1] + wsf[2] + wsf[3];

    int i0 = base + tid * 4;
#pragma unroll
    for (int k = 0; k < 4; ++k) {
        int i = i0 + k;
        if (i < n) arr[i] += P;
    }
}

// XCD-partitioned scatter: partition p = bid&7 (dispatch round-robin = XCD
// proxy) owns hyperedge slice [p*6250,..) and node slice [p*12500,..); its
// sn/sh writes land in one ~400KB region resident in its own L2 -> single
// writeback per line instead of cross-XCD 64B-line ping-pong (R2: 107MB WRITE).
__device__ __forceinline__ void scatter_body(
    const int* __restrict__ nodes, const int* __restrict__ hyper,
    int* __restrict__ off, int* __restrict__ sn, int* __restrict__ sh,
    int bid, int tid)
{
    int part = bid & (SC_PARTS - 1);
    int sub  = bid >> 3;
    int elo = part * E_SLICE;
    int nlo = part * N_SLICE;
    int i0 = sub * SC_CHUNK;
    int* off_e = off;
    int* off_n = off + E_HYPER;
    for (int i = i0 + tid; i < i0 + SC_CHUNK; i += 256) {
        int nd = nodes[i], hy = hyper[i];
        if ((unsigned)(hy - elo) < (unsigned)E_SLICE) {
            int p = atomicAdd(&off_e[hy], 1); sn[p] = nd;
        }
        if ((unsigned)(nd - nlo) < (unsigned)N_SLICE) {
            int q = atomicAdd(&off_n[nd], 1); sh[q] = hy;
        }
    }
}

__device__ __forceinline__ void zero_body(int* __restrict__ buf, int b, int tid)
{
    int idx = b * 256 + tid;
    if (idx < 150000 / 4) ((int4*)buf)[idx] = make_int4(0, 0, 0, 0);
}

// ---------------------------------------------------------------------------
// gather bodies (CSR, 8 segments/wave, R2-proven)
// ---------------------------------------------------------------------------
__device__ __forceinline__ void ge_body(
    const __hip_bfloat16* __restrict__ h,
    const int* __restrict__ sn, const int* __restrict__ off_e,
    __hip_bfloat16* __restrict__ e, int bid, int tid)
{
    int lane = tid & 63;
    int wid = bid * 4 + (tid >> 6);
    int nW  = GE_BLOCKS * 4;
    for (int s0 = wid * 8; s0 < E_HYPER; s0 += nW * 8) {
        int pos[8], end8[8], cnt8[8]; float acc[8];
#pragma unroll
        for (int c = 0; c < 8; ++c) {
            int sg = s0 + c;
            if (sg < E_HYPER) {
                pos[c]  = (sg == 0) ? 0 : off_e[sg - 1];
                end8[c] = off_e[sg];
            } else { pos[c] = 0; end8[c] = 0; }
            cnt8[c] = end8[c] - pos[c];
            acc[c] = 0.f;
        }
        while (true) {
            bool any = false;
#pragma unroll
            for (int c = 0; c < 8; ++c) any = any || (pos[c] < end8[c]);
            if (!any) break;
            int id[8];
#pragma unroll
            for (int c = 0; c < 8; ++c)
                if (pos[c] < end8[c]) id[c] = sn[pos[c]];
#pragma unroll
            for (int c = 0; c < 8; ++c)
                if (pos[c] < end8[c]) {
                    acc[c] += __bfloat162float(h[(size_t)id[c] * DIM + lane]);
                    pos[c]++;
                }
        }
#pragma unroll
        for (int c = 0; c < 8; ++c) {
            int sg = s0 + c;
            if (sg < E_HYPER)
                e[(size_t)sg * DIM + lane] =
                    __float2bfloat16(acc[c] / (float)max(cnt8[c], 1));
        }
    }
}

__device__ __forceinline__ void gn_body(
    const __hip_bfloat16* __restrict__ e,
    const int* __restrict__ sh, const int* __restrict__ off_n,
    float* __restrict__ dy, void* __restrict__ out, float* __restrict__ cws,
    int f, int use_ws, int to_carry, int bid, int tid)
{
    int lane = tid & 63;
    int wid = bid * 4 + (tid >> 6);
    int nW  = GN_BLOCKS * 4;
    for (int s0 = wid * 8; s0 < N_USERS; s0 += nW * 8) {
        int pos[8], end8[8], cnt8[8]; float acc[8];
#pragma unroll
        for (int c = 0; c < 8; ++c) {
            int sg = s0 + c;
            if (sg < N_USERS) {
                pos[c]  = (sg == 0) ? 0 : off_n[sg - 1];
                end8[c] = off_n[sg];
            } else { pos[c] = 0; end8[c] = 0; }
            cnt8[c] = end8[c] - pos[c];
            acc[c] = 0.f;
        }
        while (true) {
            bool any = false;
#pragma unroll
            for (int c = 0; c < 8; ++c) any = any || (pos[c] < end8[c]);
            if (!any) break;
            int hy[8];
#pragma unroll
            for (int c = 0; c < 8; ++c)
                if (pos[c] < end8[c]) hy[c] = sh[pos[c]];
#pragma unroll
            for (int c = 0; c < 8; ++c)
                if (pos[c] < end8[c]) {
                    acc[c] += __bfloat162float(e[(size_t)hy[c] * DIM + lane]);
                    pos[c]++;
                }
        }
#pragma unroll
        for (int c = 0; c < 8; ++c) {
            int sg = s0 + c;
            if (sg < N_USERS) {
                float v = acc[c] / (float)max(cnt8[c], 1);
                size_t o = (size_t)sg * DIM + lane;
                if (to_carry) st_carry(out, cws, o, f, use_ws, v);
                else          dy[o] = v;
            }
        }
    }
}

// ---------------------------------------------------------------------------
// fuse body: carry = softmax-blend(carry, dy) via MFMA 16x16x32 bf16
// ---------------------------------------------------------------------------
__device__ __forceinline__ void fu_body(
    void* __restrict__ dout, float* __restrict__ cws,
    const float* __restrict__ dy_buf, const float* __restrict__ st,
    int f, int use_ws, int write_out, int bid, int nblocks, int tid)
{
    float* cf = f ? (float*)dout : (use_ws ? cws : (float*)0);
    __hip_bfloat16* cb = (__hip_bfloat16*)dout;

    int lane = tid & 63;
    int quad = lane >> 4;
    int m    = lane & 15;

    bf16x8 bw[4][2];
    float b1v[4], w2v[4];
#pragma unroll
    for (int nt = 0; nt < 4; ++nt) {
#pragma unroll
        for (int kb = 0; kb < 2; ++kb)
#pragma unroll
            for (int j = 0; j < 8; ++j) {
                int k = kb * 32 + quad * 8 + j;
                bw[nt][kb][j] = (__bf16)st[4160 + k * 64 + nt * 16 + m];
            }
        b1v[nt] = st[8256 + nt * 16 + m];
        w2v[nt] = st[8320 + nt * 16 + m];
    }

    int wid = bid * 4 + (tid >> 6);
    int nW  = nblocks * 4;
    const int NT = N_USERS / 16;

    for (int tile = wid; tile < NT; tile += nW) {
        int row = tile * 16 + m;
        size_t base = (size_t)row * DIM;

        float hidf[2][8], dyf[2][8];
        if (cf) {
            const f32x4* cp = (const f32x4*)(cf + base);
            const f32x4* dp = (const f32x4*)(dy_buf + base);
#pragma unroll
            for (int kb = 0; kb < 2; ++kb) {
                f32x4 a = cp[kb * 8 + quad * 2], b = cp[kb * 8 + quad * 2 + 1];
                f32x4 c = dp[kb * 8 + quad * 2], d = dp[kb * 8 + quad * 2 + 1];
#pragma unroll
                for (int j = 0; j < 4; ++j) {
                    hidf[kb][j] = a[j]; hidf[kb][4 + j] = b[j];
                    dyf[kb][j]  = c[j]; dyf[kb][4 + j]  = d[j];
                }
            }
        } else {
#pragma unroll
            for (int kb = 0; kb < 2; ++kb)
#pragma unroll
                for (int j = 0; j < 8; ++j) {
                    int k = kb * 32 + quad * 8 + j;
                    hidf[kb][j] = __bfloat162float(cb[base + k]);
                    dyf[kb][j]  = dy_buf[base + k];
                }
        }

        bf16x8 ah[2], ad[2];
#pragma unroll
        for (int kb = 0; kb < 2; ++kb)
#pragma unroll
            for (int j = 0; j < 8; ++j) {
                ah[kb][j] = (__bf16)hidf[kb][j];
                ad[kb][j] = (__bf16)dyf[kb][j];
            }

        float zh[4] = {0.f, 0.f, 0.f, 0.f};
        float zd[4] = {0.f, 0.f, 0.f, 0.f};
#pragma unroll
        for (int nt = 0; nt < 4; ++nt) {
            f32x4 acch = {0.f, 0.f, 0.f, 0.f};
            f32x4 accd = {0.f, 0.f, 0.f, 0.f};
#pragma unroll
            for (int kb = 0; kb < 2; ++kb) {
                acch = __builtin_amdgcn_mfma_f32_16x16x32_bf16(ah[kb], bw[nt][kb], acch, 0, 0, 0);
                accd = __builtin_amdgcn_mfma_f32_16x16x32_bf16(ad[kb], bw[nt][kb], accd, 0, 0, 0);
            }
#pragma unroll
            for (int reg = 0; reg < 4; ++reg) {
                zh[reg] += tanhf(acch[reg] + b1v[nt]) * w2v[nt];
                zd[reg] += tanhf(accd[reg] + b1v[nt]) * w2v[nt];
            }
        }
        float s[4];
#pragma unroll
        for (int reg = 0; reg < 4; ++reg) {
#pragma unroll
            for (int off = 1; off < 16; off <<= 1) {
                zh[reg] += __shfl_xor(zh[reg], off, 64);
                zd[reg] += __shfl_xor(zd[reg], off, 64);
            }
            float mm = fmaxf(zh[reg], zd[reg]);
            float eh = expf(zh[reg] - mm), ed = expf(zd[reg] - mm);
            s[reg] = eh / (eh + ed);
        }
        int srcl = (m >> 2) * 16;
        float s0 = __shfl(s[0], srcl, 64), s1 = __shfl(s[1], srcl, 64);
        float s2 = __shfl(s[2], srcl, 64), s3 = __shfl(s[3], srcl, 64);
        int r3 = m & 3;
        float sv = (r3 == 0) ? s0 : (r3 == 1) ? s1 : (r3 == 2) ? s2 : s3;

        if (cf) {
            f32x4* cp = (f32x4*)(cf + base);
#pragma unroll
            for (int kb = 0; kb < 2; ++kb) {
                f32x4 v0, v1;
#pragma unroll
                for (int j = 0; j < 4; ++j) {
                    v0[j] = sv * hidf[kb][j]     + (1.f - sv) * dyf[kb][j];
                    v1[j] = sv * hidf[kb][4 + j] + (1.f - sv) * dyf[kb][4 + j];
                }
                cp[kb * 8 + quad * 2]     = v0;
                cp[kb * 8 + quad * 2 + 1] = v1;
                if (write_out && !f) {
#pragma unroll
                    for (int j = 0; j < 4; ++j) {
                        int k = kb * 32 + quad * 8 + j;
                        cb[base + k]     = __float2bfloat16(v0[j]);
                        cb[base + k + 4] = __float2bfloat16(v1[j]);
                    }
                }
            }
        } else {
#pragma unroll
            for (int kb = 0; kb < 2; ++kb)
#pragma unroll
                for (int j = 0; j < 8; ++j) {
                    int k = kb * 32 + quad * 8 + j;
                    float v = sv * hidf[kb][j] + (1.f - sv) * dyf[kb][j];
                    cb[base + k] = __float2bfloat16(v);
                }
        }
    }
}

// ---------------------------------------------------------------------------
// Standalone kernels (prologue)
// ---------------------------------------------------------------------------
__global__ __launch_bounds__(256) void k_zero_all(int* __restrict__ base)
{
    int idx = blockIdx.x * 256 + threadIdx.x;
    if (idx < 300000 / 4) ((int4*)base)[idx] = make_int4(0, 0, 0, 0);
}

__global__ __launch_bounds__(256) void k_trans_hist(
    const void* __restrict__ emb, const int* __restrict__ flag,
    const float* __restrict__ st, __hip_bfloat16* __restrict__ h,
    const int* __restrict__ nodes, const int* __restrict__ hyper,
    int* __restrict__ off)
{
    __shared__ float Wl[DIM * DIM];
    __shared__ float bl[DIM];
    if ((int)blockIdx.x < TR_BLOCKS) {
        for (int i = threadIdx.x; i < DIM * DIM; i += blockDim.x) Wl[i] = st[i];
        if (threadIdx.x < DIM) bl[threadIdx.x] = st[4096 + threadIdx.x];
        __syncthreads();
        int f = *flag;
        int wave = threadIdx.x >> 6, lane = threadIdx.x & 63;
        int nW = TR_BLOCKS * 4;
        for (int row = blockIdx.x * 4 + wave; row < N_USERS; row += nW) {
            size_t base = (size_t)row * DIM;
            float v = ld_in(emb, base + lane, f);
            float acc = bl[lane];
#pragma unroll
            for (int k = 0; k < DIM; ++k)
                acc += __shfl(v, k, 64) * Wl[k * DIM + lane];
            h[base + lane] = __float2bfloat16(fmaxf(acc, 0.f));
        }
    } else {
        int i = (blockIdx.x - TR_BLOCKS) * blockDim.x + threadIdx.x;
        hist_body(nodes, hyper, off, i);
    }
}

__global__ __launch_bounds__(256) void k_scan1(
    int* __restrict__ off, int* __restrict__ bsum)
{
    scan1_body(off, bsum, blockIdx.x, threadIdx.x);
}

__global__ __launch_bounds__(256) void k_scan_fix(
    int* __restrict__ off, const int* __restrict__ bsum)
{
    fix_body(off, bsum, blockIdx.x, threadIdx.x);
}

// ---------------------------------------------------------------------------
// K1: gather_e(t) || hist(t+1)
// ---------------------------------------------------------------------------
__global__ __launch_bounds__(256) void k_ge_hist(
    const __hip_bfloat16* __restrict__ h,
    const int* __restrict__ sn, const int* __restrict__ off_cur,
    __hip_bfloat16* __restrict__ e,
    const int* __restrict__ nodes1, const int* __restrict__ hyper1,
    int* __restrict__ off_nxt, int do_hist)
{
    if ((int)blockIdx.x < GE_BLOCKS)
        ge_body(h, sn, off_cur, e, blockIdx.x, threadIdx.x);
    else if (do_hist)
        hist_body(nodes1, hyper1, off_nxt,
                  (blockIdx.x - GE_BLOCKS) * 256 + threadIdx.x);
}

// ---------------------------------------------------------------------------
// K2: gather_n(t) || scan1(t+1)
// ---------------------------------------------------------------------------
__global__ __launch_bounds__(256) void k_gn_scan(
    const __hip_bfloat16* __restrict__ e,
    const int* __restrict__ sh, const int* __restrict__ off_cur,
    float* __restrict__ dy, void* __restrict__ out, float* __restrict__ cws,
    const int* __restrict__ flag, int use_ws, int to_carry,
    int* __restrict__ off_nxt, int* __restrict__ bsum, int do_scan)
{
    if ((int)blockIdx.x < GN_BLOCKS)
        gn_body(e, sh, off_cur + E_HYPER, dy, out, cws, *flag, use_ws,
                to_carry, blockIdx.x, threadIdx.x);
    else if (do_scan)
        scan1_body(off_nxt, bsum, blockIdx.x - GN_BLOCKS, threadIdx.x);
}

// ---------------------------------------------------------------------------
// K3: fuse(t) || scan_fix(t+1)
// ---------------------------------------------------------------------------
__global__ __launch_bounds__(256) void k_fuse_fix(
    void* __restrict__ dout, float* __restrict__ cws,
    const float* __restrict__ dy_buf, const float* __restrict__ st,
    const int* __restrict__ flag, int use_ws, int write_out, int nfuse,
    int* __restrict__ off_nxt, const int* __restrict__ bsum, int do_fix)
{
    if ((int)blockIdx.x < nfuse)
        fu_body(dout, cws, dy_buf, st, *flag, use_ws, write_out,
                blockIdx.x, nfuse, threadIdx.x);
    else if (do_fix)
        fix_body(off_nxt, bsum, blockIdx.x - nfuse, threadIdx.x);
}

// ---------------------------------------------------------------------------
// K4: scatter(t+1) [XCD-partitioned] || zero(off_cur for t+2)
// ---------------------------------------------------------------------------
__global__ __launch_bounds__(256) void k_scatter_zero(
    const int* __restrict__ nodes1, const int* __restrict__ hyper1,
    int* __restrict__ off_nxt, int* __restrict__ sn, int* __restrict__ sh,
    int* __restrict__ off_zero, int do_zero)
{
    if ((int)blockIdx.x < SC_BLOCKS)
        scatter_body(nodes1, hyper1, off_nxt, sn, sh, blockIdx.x, threadIdx.x);
    else if (do_zero)
        zero_body(off_zero, blockIdx.x - SC_BLOCKS, threadIdx.x);
}

// ---------------------------------------------------------------------------
extern "C" void kernel_launch(void* const* d_in, const int* in_sizes, int n_in,
                              void* d_out, int out_size, void* d_ws,
                              size_t ws_size, hipStream_t stream)
{
    const void* user_emb = d_in[0];
    const void* W_conv   = d_in[1];
    const void* b_conv   = d_in[2];
    const void* fus_w1   = d_in[3];
    const void* fus_b1   = d_in[4];
    const void* fus_w2   = d_in[5];
    const void* fus_b2   = d_in[6];
    const int* edge_nodes = (const int*)d_in[7];
    const int* edge_hyper = (const int*)d_in[8];

    const size_t ND = (size_t)N_USERS * DIM;

    // ws layout (fp32 word offsets):
    //   0        : flag
    //   16       : st [8448]
    //   8720     : offA int [150000]  (e[0..50000) | n[50000..150000))
    //   158720   : offB int [150000]
    //   308720   : sn int [800000]    (first 256 words double as scan bsum —
    //                                  sn dead during K2/K3, rewritten by K4)
    //   1108720  : sh int [800000]
    //   1908720  : e bf16 [E*D]
    //   3508720  : dy fp32 [N*D]
    //   9908720  : h bf16 [N*D]
    //   13108720 : optional fp32 carry [N*D] (unused when f=1: carry in d_out)
    float* ws = (float*)d_ws;
    int*   flag   = (int*)ws;
    float* st     = ws + 16;
    int*   offA   = (int*)(ws + 8720);
    int*   offB   = (int*)(ws + 158720);
    int*   sn     = (int*)(ws + 308720);
    int*   bsum   = sn;                       // alias (see layout note)
    int*   sh     = (int*)(ws + 1108720);
    __hip_bfloat16* e_buf = (__hip_bfloat16*)(ws + 1908720);
    float* dy_buf = ws + 3508720;
    __hip_bfloat16* h = (__hip_bfloat16*)(ws + 9908720);
    float* carry_ws   = ws + 13108720;

    const size_t need_ws_carry = (13108720 + ND) * 4;
    const int use_ws = (ws_size >= need_ws_carry) ? 1 : 0;

    int* offs[2] = { offA, offB };

    k_detect<<<1, 256, 0, stream>>>((const unsigned short*)user_emb, flag);
    k_convert_params<<<(8385 + 255) / 256, 256, 0, stream>>>(
        W_conv, b_conv, fus_w1, fus_b1, fus_w2, fus_b2, flag, st);

    // prologue: zero both off buffers; transform || hist(0); scan; scatter(0)
    k_zero_all<<<ZALL_BLKS, 256, 0, stream>>>(offA);
    k_trans_hist<<<TR_BLOCKS + HS_BLOCKS, 256, 0, stream>>>(
        user_emb, flag, st, h, edge_nodes, edge_hyper, offA);
    k_scan1<<<SCAN_BLKS, 256, 0, stream>>>(offA, bsum);
    k_scan_fix<<<SCAN_BLKS, 256, 0, stream>>>(offA, bsum);
    k_scatter_zero<<<SC_BLOCKS, 256, 0, stream>>>(
        edge_nodes, edge_hyper, offA, sn, sh, offB, 0);

    for (int t = 0; t < T_STEPS; ++t) {
        const int* nodes1 = edge_nodes + (size_t)(t + 1) * NNZ_E;
        const int* hyper1 = edge_hyper + (size_t)(t + 1) * NNZ_E;
        int cur = t & 1, nxt = cur ^ 1;
        int do_b = (t < T_STEPS - 1) ? 1 : 0;

        k_ge_hist<<<GE_BLOCKS + (do_b ? HS_BLOCKS : 0), 256, 0, stream>>>(
            h, sn, offs[cur], e_buf, nodes1, hyper1, offs[nxt], do_b);

        k_gn_scan<<<GN_BLOCKS + (do_b ? SCAN_BLKS : 0), 256, 0, stream>>>(
            e_buf, sh, offs[cur], dy_buf, d_out, carry_ws, flag, use_ws,
            (t == 0) ? 1 : 0, offs[nxt], bsum, do_b);

        int nfuse = (t > 0) ? FU_BLOCKS : 0;
        int g3 = nfuse + (do_b ? SCAN_BLKS : 0);
        if (g3 > 0)
            k_fuse_fix<<<g3, 256, 0, stream>>>(
                d_out, carry_ws, dy_buf, st, flag, use_ws,
                (t == T_STEPS - 1) ? 1 : 0, nfuse, offs[nxt], bsum, do_b);

        if (do_b)
            k_scatter_zero<<<SC_BLOCKS + ZERO_BLKS, 256, 0, stream>>>(
                nodes1, hyper1, offs[nxt], sn, sh, offs[cur], 1);
    }
}

// Round 4
// 2305.172 us; speedup vs baseline: 1.5985x; 1.0314x over previous
//
#include <hip/hip_runtime.h>
#include <hip/hip_bf16.h>

#define N_USERS 100000
#define E_HYPER 50000
#define NNZ_E   800000
#define T_STEPS 8
#define DIM     64

#define CAP_E   64
#define CAP_N   44

#define TR_BLOCKS  1024
#define GE_BLOCKS  1563
#define GNF_BLOCKS 1563
#define ZERO_BLKS  147

#define SC_PARTS   8
#define SC_SUB     256
#define SC_BLOCKS  (SC_PARTS * SC_SUB)   // 2048
#define SC_CHUNK   (NNZ_E / SC_SUB)      // 3125
#define E_SLICE    (E_HYPER / SC_PARTS)  // 6250
#define N_SLICE    (N_USERS / SC_PARTS)  // 12500

typedef __bf16 bf16x8 __attribute__((ext_vector_type(8)));
typedef float  f32x4  __attribute__((ext_vector_type(4)));

// ---------------------------------------------------------------------------
__device__ __forceinline__ float ld_in(const void* p, size_t i, int f32)
{
    return f32 ? ((const float*)p)[i]
               : __bfloat162float(((const __hip_bfloat16*)p)[i]);
}

// carry store: f32-in-dout(f=1) | f32-in-ws | bf16-in-dout
__device__ __forceinline__ void st_carry(void* out, float* cws, size_t i,
                                         int f, int use_ws, float v)
{
    if (f) { ((float*)out)[i] = v; return; }
    if (use_ws) { cws[i] = v; return; }
    ((__hip_bfloat16*)out)[i] = __float2bfloat16(v);
}

// ---------------------------------------------------------------------------
// Kernel 0: input dtype detector
// ---------------------------------------------------------------------------
__global__ void k_detect(const unsigned short* __restrict__ raw, int* __restrict__ flag)
{
    __shared__ int cnt;
    if (threadIdx.x == 0) cnt = 0;
    __syncthreads();
    int c = 0;
    for (int i = threadIdx.x; i < 4096; i += blockDim.x) {
        int e = (raw[i] >> 7) & 0xFF;
        if (e > 126) c++;
    }
    atomicAdd(&cnt, c);
    __syncthreads();
    if (threadIdx.x == 0) *flag = (cnt > 64) ? 1 : 0;
}

// ---------------------------------------------------------------------------
// Kernel 0b: params -> fp32 staging
// st: W[0,4096) b[4096,4160) w1[4160,8256) b1[8256,8320) w2[8320,8384) b2[8384]
// ---------------------------------------------------------------------------
__global__ void k_convert_params(
    const void* W, const void* b, const void* w1, const void* b1,
    const void* w2, const void* b2, const int* __restrict__ flag,
    float* __restrict__ st)
{
    int f = *flag;
    int i = blockIdx.x * blockDim.x + threadIdx.x;
    if (i < 4096)          st[i] = ld_in(W,  i,        f);
    else if (i < 4160)     st[i] = ld_in(b,  i - 4096, f);
    else if (i < 8256)     st[i] = ld_in(w1, i - 4160, f);
    else if (i < 8320)     st[i] = ld_in(b1, i - 8256, f);
    else if (i < 8384)     st[i] = ld_in(w2, i - 8320, f);
    else if (i == 8384)    st[i] = ld_in(b2, 0,        f);
}

// ---------------------------------------------------------------------------
// Padded atomic-append (hist+scatter fused, XCD-partitioned writes).
// counts slab layout: [0,E_HYPER) = per-hyperedge, [E_HYPER,+N_USERS) = per-node.
// rank = atomicAdd(count) doubles as slot index: ONE atomic pass per list.
// ---------------------------------------------------------------------------
__device__ __forceinline__ void appendE_body(
    const int* __restrict__ nodes, const int* __restrict__ hyper,
    int* __restrict__ cnt, int* __restrict__ sn_pad, int bid, int tid)
{
    int part = bid & (SC_PARTS - 1);
    int sub  = bid >> 3;
    int elo  = part * E_SLICE;
    int i0   = sub * SC_CHUNK;
    for (int i = i0 + tid; i < i0 + SC_CHUNK; i += 256) {
        int hy = hyper[i];
        if ((unsigned)(hy - elo) < (unsigned)E_SLICE) {
            int r = atomicAdd(&cnt[hy], 1);
            if (r < CAP_E) sn_pad[hy * CAP_E + r] = nodes[i];
        }
    }
}

__device__ __forceinline__ void appendN_body(
    const int* __restrict__ nodes, const int* __restrict__ hyper,
    int* __restrict__ cnt, int* __restrict__ sh_pad, int bid, int tid)
{
    int part = bid & (SC_PARTS - 1);
    int sub  = bid >> 3;
    int nlo  = part * N_SLICE;
    int i0   = sub * SC_CHUNK;
    for (int i = i0 + tid; i < i0 + SC_CHUNK; i += 256) {
        int nd = nodes[i];
        if ((unsigned)(nd - nlo) < (unsigned)N_SLICE) {
            int r = atomicAdd(&cnt[E_HYPER + nd], 1);
            if (r < CAP_N) sh_pad[nd * CAP_N + r] = hyper[i];
        }
    }
}

__device__ __forceinline__ void zero_body(int* __restrict__ buf, int b, int tid)
{
    int idx = b * 256 + tid;
    if (idx < 150000 / 4) ((int4*)buf)[idx] = make_int4(0, 0, 0, 0);
}

// ---------------------------------------------------------------------------
// gather_e body (padded CSR, 8 segments/wave — R2-proven loop shape)
// ---------------------------------------------------------------------------
__device__ __forceinline__ void ge_body(
    const __hip_bfloat16* __restrict__ h,
    const int* __restrict__ sn_pad, const int* __restrict__ cnt_e,
    __hip_bfloat16* __restrict__ e, int bid, int tid)
{
    int lane = tid & 63;
    int wid = bid * 4 + (tid >> 6);
    int nW  = GE_BLOCKS * 4;
    for (int s0 = wid * 8; s0 < E_HYPER; s0 += nW * 8) {
        int pos[8], end8[8], cnt8[8]; float acc[8];
#pragma unroll
        for (int c = 0; c < 8; ++c) {
            int sg = s0 + c;
            int cc = (sg < E_HYPER) ? cnt_e[sg] : 0;
            cnt8[c] = cc;
            pos[c]  = sg * CAP_E;
            end8[c] = pos[c] + min(cc, CAP_E);
            acc[c]  = 0.f;
        }
        while (true) {
            bool any = false;
#pragma unroll
            for (int c = 0; c < 8; ++c) any = any || (pos[c] < end8[c]);
            if (!any) break;
            int id[8];
#pragma unroll
            for (int c = 0; c < 8; ++c)
                if (pos[c] < end8[c]) id[c] = sn_pad[pos[c]];
#pragma unroll
            for (int c = 0; c < 8; ++c)
                if (pos[c] < end8[c]) {
                    acc[c] += __bfloat162float(h[(size_t)id[c] * DIM + lane]);
                    pos[c]++;
                }
        }
#pragma unroll
        for (int c = 0; c < 8; ++c) {
            int sg = s0 + c;
            if (sg < E_HYPER)
                e[(size_t)sg * DIM + lane] =
                    __float2bfloat16(acc[c] / (float)max(cnt8[c], 1));
        }
    }
}

// ---------------------------------------------------------------------------
// fuse tile: ONE 16-row tile at global rows [row0,row0+16), dy from LDS
// (stride 68 floats). Math verbatim from R5/R7-proven fu_body.
// ---------------------------------------------------------------------------
__device__ __forceinline__ void fu_tile(
    void* __restrict__ dout, float* __restrict__ cws,
    const float* __restrict__ dyl_t, const float* __restrict__ st,
    int f, int use_ws, int write_out, int row0, int tid)
{
    float* cf = f ? (float*)dout : (use_ws ? cws : (float*)0);
    __hip_bfloat16* cb = (__hip_bfloat16*)dout;

    int lane = tid & 63;
    int quad = lane >> 4;
    int m    = lane & 15;

    bf16x8 bw[4][2];
    float b1v[4], w2v[4];
#pragma unroll
    for (int nt = 0; nt < 4; ++nt) {
#pragma unroll
        for (int kb = 0; kb < 2; ++kb)
#pragma unroll
            for (int j = 0; j < 8; ++j) {
                int k = kb * 32 + quad * 8 + j;
                bw[nt][kb][j] = (__bf16)st[4160 + k * 64 + nt * 16 + m];
            }
        b1v[nt] = st[8256 + nt * 16 + m];
        w2v[nt] = st[8320 + nt * 16 + m];
    }

    int row = row0 + m;
    size_t base = (size_t)row * DIM;

    float hidf[2][8], dyf[2][8];
    const f32x4* dp = (const f32x4*)(dyl_t + m * 68);
    if (cf) {
        const f32x4* cp = (const f32x4*)(cf + base);
#pragma unroll
        for (int kb = 0; kb < 2; ++kb) {
            f32x4 a = cp[kb * 8 + quad * 2], b = cp[kb * 8 + quad * 2 + 1];
            f32x4 c = dp[kb * 8 + quad * 2], d = dp[kb * 8 + quad * 2 + 1];
#pragma unroll
            for (int j = 0; j < 4; ++j) {
                hidf[kb][j] = a[j]; hidf[kb][4 + j] = b[j];
                dyf[kb][j]  = c[j]; dyf[kb][4 + j]  = d[j];
            }
        }
    } else {
#pragma unroll
        for (int kb = 0; kb < 2; ++kb)
#pragma unroll
            for (int j = 0; j < 8; ++j) {
                int k = kb * 32 + quad * 8 + j;
                hidf[kb][j] = __bfloat162float(cb[base + k]);
                dyf[kb][j]  = dyl_t[m * 68 + k];
            }
    }

    bf16x8 ah[2], ad[2];
#pragma unroll
    for (int kb = 0; kb < 2; ++kb)
#pragma unroll
        for (int j = 0; j < 8; ++j) {
            ah[kb][j] = (__bf16)hidf[kb][j];
            ad[kb][j] = (__bf16)dyf[kb][j];
        }

    float zh[4] = {0.f, 0.f, 0.f, 0.f};
    float zd[4] = {0.f, 0.f, 0.f, 0.f};
#pragma unroll
    for (int nt = 0; nt < 4; ++nt) {
        f32x4 acch = {0.f, 0.f, 0.f, 0.f};
        f32x4 accd = {0.f, 0.f, 0.f, 0.f};
#pragma unroll
        for (int kb = 0; kb < 2; ++kb) {
            acch = __builtin_amdgcn_mfma_f32_16x16x32_bf16(ah[kb], bw[nt][kb], acch, 0, 0, 0);
            accd = __builtin_amdgcn_mfma_f32_16x16x32_bf16(ad[kb], bw[nt][kb], accd, 0, 0, 0);
        }
#pragma unroll
        for (int reg = 0; reg < 4; ++reg) {
            zh[reg] += tanhf(acch[reg] + b1v[nt]) * w2v[nt];
            zd[reg] += tanhf(accd[reg] + b1v[nt]) * w2v[nt];
        }
    }
    float s[4];
#pragma unroll
    for (int reg = 0; reg < 4; ++reg) {
#pragma unroll
        for (int off = 1; off < 16; off <<= 1) {
            zh[reg] += __shfl_xor(zh[reg], off, 64);
            zd[reg] += __shfl_xor(zd[reg], off, 64);
        }
        float mm = fmaxf(zh[reg], zd[reg]);
        float eh = expf(zh[reg] - mm), ed = expf(zd[reg] - mm);
        s[reg] = eh / (eh + ed);
    }
    int srcl = (m >> 2) * 16;
    float s0 = __shfl(s[0], srcl, 64), s1 = __shfl(s[1], srcl, 64);
    float s2 = __shfl(s[2], srcl, 64), s3 = __shfl(s[3], srcl, 64);
    int r3 = m & 3;
    float sv = (r3 == 0) ? s0 : (r3 == 1) ? s1 : (r3 == 2) ? s2 : s3;

    if (cf) {
        f32x4* cp = (f32x4*)(cf + base);
#pragma unroll
        for (int kb = 0; kb < 2; ++kb) {
            f32x4 v0, v1;
#pragma unroll
            for (int j = 0; j < 4; ++j) {
                v0[j] = sv * hidf[kb][j]     + (1.f - sv) * dyf[kb][j];
                v1[j] = sv * hidf[kb][4 + j] + (1.f - sv) * dyf[kb][4 + j];
            }
            cp[kb * 8 + quad * 2]     = v0;
            cp[kb * 8 + quad * 2 + 1] = v1;
            if (write_out && !f) {
#pragma unroll
                for (int j = 0; j < 4; ++j) {
                    int k = kb * 32 + quad * 8 + j;
                    cb[base + k]     = __float2bfloat16(v0[j]);
                    cb[base + k + 4] = __float2bfloat16(v1[j]);
                }
            }
        }
    } else {
#pragma unroll
        for (int kb = 0; kb < 2; ++kb)
#pragma unroll
            for (int j = 0; j < 8; ++j) {
                int k = kb * 32 + quad * 8 + j;
                float v = sv * hidf[kb][j] + (1.f - sv) * dyf[kb][j];
                cb[base + k] = __float2bfloat16(v);
            }
    }
}

// ---------------------------------------------------------------------------
// Prologue: zero counts slabs 0 and 1
// ---------------------------------------------------------------------------
__global__ __launch_bounds__(256) void k_zero2(int* __restrict__ c0, int* __restrict__ c1)
{
    if ((int)blockIdx.x < ZERO_BLKS) zero_body(c0, blockIdx.x, threadIdx.x);
    else                             zero_body(c1, blockIdx.x - ZERO_BLKS, threadIdx.x);
}

// ---------------------------------------------------------------------------
// Prologue: transform || append-E(0)
// ---------------------------------------------------------------------------
__global__ __launch_bounds__(256) void k_trans_appendE(
    const void* __restrict__ emb, const int* __restrict__ flag,
    const float* __restrict__ st, __hip_bfloat16* __restrict__ h,
    const int* __restrict__ nodes, const int* __restrict__ hyper,
    int* __restrict__ cnt, int* __restrict__ sn_pad)
{
    __shared__ float Wl[DIM * DIM];
    __shared__ float bl[DIM];
    if ((int)blockIdx.x < TR_BLOCKS) {
        for (int i = threadIdx.x; i < DIM * DIM; i += blockDim.x) Wl[i] = st[i];
        if (threadIdx.x < DIM) bl[threadIdx.x] = st[4096 + threadIdx.x];
        __syncthreads();
        int f = *flag;
        int wave = threadIdx.x >> 6, lane = threadIdx.x & 63;
        int nW = TR_BLOCKS * 4;
        for (int row = blockIdx.x * 4 + wave; row < N_USERS; row += nW) {
            size_t base = (size_t)row * DIM;
            float v = ld_in(emb, base + lane, f);
            float acc = bl[lane];
#pragma unroll
            for (int k = 0; k < DIM; ++k)
                acc += __shfl(v, k, 64) * Wl[k * DIM + lane];
            h[base + lane] = __float2bfloat16(fmaxf(acc, 0.f));
        }
    } else {
        appendE_body(nodes, hyper, cnt, sn_pad,
                     blockIdx.x - TR_BLOCKS, threadIdx.x);
    }
}

// ---------------------------------------------------------------------------
// KA: gather_e(t) || append-N(t)   (same list: sh_pad written here, read in KB)
// ---------------------------------------------------------------------------
__global__ __launch_bounds__(256) void k_ge_appendN(
    const __hip_bfloat16* __restrict__ h,
    const int* __restrict__ sn_pad, const int* __restrict__ cnt_cur,
    __hip_bfloat16* __restrict__ e,
    const int* __restrict__ nodes, const int* __restrict__ hyper,
    int* __restrict__ cnt_w, int* __restrict__ sh_pad)
{
    if ((int)blockIdx.x < GE_BLOCKS)
        ge_body(h, sn_pad, cnt_cur, e, blockIdx.x, threadIdx.x);
    else
        appendN_body(nodes, hyper, cnt_w, sh_pad,
                     blockIdx.x - GE_BLOCKS, threadIdx.x);
}

// ---------------------------------------------------------------------------
// KB: gnfuse(t) || append-E(t+1) || zero(counts for t+2)
// gnfuse: each wave gathers 16 node-rows (two 8-chain batches) into an LDS
// tile, then runs the proven fuse math on its own tile (dy never hits HBM).
// ---------------------------------------------------------------------------
__global__ __launch_bounds__(256) void k_gnfuse(
    const __hip_bfloat16* __restrict__ e,
    const int* __restrict__ sh_pad, const int* __restrict__ cnt_n,
    void* __restrict__ dout, float* __restrict__ cws,
    const float* __restrict__ st, const int* __restrict__ flag,
    int use_ws, int to_carry, int write_out,
    const int* __restrict__ nodes1, const int* __restrict__ hyper1,
    int* __restrict__ cnt_nxt, int* __restrict__ sn_pad, int nsc,
    int* __restrict__ cnt_zero, int nzero)
{
    __shared__ float dyl[64 * 68];
    int b = blockIdx.x, tid = threadIdx.x;
    if (b < GNF_BLOCKS) {
        int f = *flag;
        int lane = tid & 63, w = tid >> 6;
        int row0 = b * 64 + w * 16;
        for (int bb = 0; bb < 2; ++bb) {
            int bs = row0 + bb * 8;
            int pos[8], end8[8], cnt8[8]; float acc[8];
#pragma unroll
            for (int c = 0; c < 8; ++c) {
                int sg = bs + c;
                int cc = (sg < N_USERS) ? cnt_n[sg] : 0;
                cnt8[c] = cc;
                pos[c]  = sg * CAP_N;
                end8[c] = pos[c] + min(cc, CAP_N);
                acc[c]  = 0.f;
            }
            while (true) {
                bool any = false;
#pragma unroll
                for (int c = 0; c < 8; ++c) any = any || (pos[c] < end8[c]);
                if (!any) break;
                int hy[8];
#pragma unroll
                for (int c = 0; c < 8; ++c)
                    if (pos[c] < end8[c]) hy[c] = sh_pad[pos[c]];
#pragma unroll
                for (int c = 0; c < 8; ++c)
                    if (pos[c] < end8[c]) {
                        acc[c] += __bfloat162float(e[(size_t)hy[c] * DIM + lane]);
                        pos[c]++;
                    }
            }
#pragma unroll
            for (int c = 0; c < 8; ++c) {
                int sg = bs + c;
                if (sg < N_USERS) {
                    float v = acc[c] / (float)max(cnt8[c], 1);
                    if (to_carry)
                        st_carry(dout, cws, (size_t)sg * DIM + lane, f, use_ws, v);
                    else
                        dyl[(w * 16 + bb * 8 + c) * 68 + lane] = v;
                }
            }
        }
        __syncthreads();
        if (!to_carry && row0 + 16 <= N_USERS)
            fu_tile(dout, cws, dyl + w * 16 * 68, st, f, use_ws,
                    write_out, row0, tid);
    } else if (b < GNF_BLOCKS + nsc) {
        appendE_body(nodes1, hyper1, cnt_nxt, sn_pad, b - GNF_BLOCKS, tid);
    } else if (nzero) {
        zero_body(cnt_zero, b - GNF_BLOCKS - nsc, tid);
    }
}

// ---------------------------------------------------------------------------
extern "C" void kernel_launch(void* const* d_in, const int* in_sizes, int n_in,
                              void* d_out, int out_size, void* d_ws,
                              size_t ws_size, hipStream_t stream)
{
    const void* user_emb = d_in[0];
    const void* W_conv   = d_in[1];
    const void* b_conv   = d_in[2];
    const void* fus_w1   = d_in[3];
    const void* fus_b1   = d_in[4];
    const void* fus_w2   = d_in[5];
    const void* fus_b2   = d_in[6];
    const int* edge_nodes = (const int*)d_in[7];
    const int* edge_hyper = (const int*)d_in[8];

    const size_t ND = (size_t)N_USERS * DIM;

    // ws layout (fp32 word offsets) — mandatory 51.4 MB, with carry 77.03 MB:
    //   0         : flag
    //   16        : st [8448]
    //   8464      : counts 3 slabs x 150016 ints (e[0,50K) | n[50K,150K))
    //   458512    : sn_pad int [50000*64]   (single-buffered, see schedule)
    //   3658512   : sh_pad int [100000*44]
    //   8058512   : e bf16 [E*D]
    //   9658512   : h bf16 [N*D]
    //   12858512  : optional fp32 carry [N*D]
    float* ws = (float*)d_ws;
    int*   flag   = (int*)ws;
    float* st     = ws + 16;
    int*   cnts[3];
    cnts[0] = (int*)(ws + 8464);
    cnts[1] = (int*)(ws + 8464 + 150016);
    cnts[2] = (int*)(ws + 8464 + 300032);
    int*   sn_pad = (int*)(ws + 458512);
    int*   sh_pad = (int*)(ws + 3658512);
    __hip_bfloat16* e_buf = (__hip_bfloat16*)(ws + 8058512);
    __hip_bfloat16* h     = (__hip_bfloat16*)(ws + 9658512);
    float* carry_ws       = ws + 12858512;

    const size_t need_ws_carry = (12858512 + ND) * 4;
    const int use_ws = (ws_size >= need_ws_carry) ? 1 : 0;

    k_detect<<<1, 256, 0, stream>>>((const unsigned short*)user_emb, flag);
    k_convert_params<<<(8385 + 255) / 256, 256, 0, stream>>>(
        W_conv, b_conv, fus_w1, fus_b1, fus_w2, fus_b2, flag, st);

    // prologue: zero cnt[0],cnt[1]; transform || append-E(0)
    k_zero2<<<2 * ZERO_BLKS, 256, 0, stream>>>(cnts[0], cnts[1]);
    k_trans_appendE<<<TR_BLOCKS + SC_BLOCKS, 256, 0, stream>>>(
        user_emb, flag, st, h, edge_nodes, edge_hyper, cnts[0], sn_pad);

    for (int t = 0; t < T_STEPS; ++t) {
        const int* nodes0 = edge_nodes + (size_t)t * NNZ_E;
        const int* hyper0 = edge_hyper + (size_t)t * NNZ_E;
        const int* nodes1 = edge_nodes + (size_t)(t + 1) * NNZ_E;
        const int* hyper1 = edge_hyper + (size_t)(t + 1) * NNZ_E;
        int c3 = t % 3, n3 = (t + 1) % 3, z3 = (t + 2) % 3;

        // KA: ge(t) || append-N(t)  (sh_pad for list t, read next dispatch)
        k_ge_appendN<<<GE_BLOCKS + SC_BLOCKS, 256, 0, stream>>>(
            h, sn_pad, cnts[c3], e_buf, nodes0, hyper0, cnts[c3], sh_pad);

        // KB: gnfuse(t) || append-E(t+1) || zero(cnt for t+2)
        int nsc = (t < T_STEPS - 1) ? SC_BLOCKS : 0;
        int nz  = (t < T_STEPS - 2) ? ZERO_BLKS : 0;
        k_gnfuse<<<GNF_BLOCKS + nsc + nz, 256, 0, stream>>>(
            e_buf, sh_pad, cnts[c3] + E_HYPER,
            d_out, carry_ws, st, flag, use_ws,
            (t == 0) ? 1 : 0, (t == T_STEPS - 1) ? 1 : 0,
            nodes1, hyper1, cnts[n3], sn_pad, nsc, cnts[z3], nz);
    }
}

// Round 5
// 2277.976 us; speedup vs baseline: 1.6175x; 1.0119x over previous
//
#include <hip/hip_runtime.h>
#include <hip/hip_bf16.h>

#define N_USERS 100000
#define E_HYPER 50000
#define NNZ_E   800000
#define T_STEPS 8
#define DIM     64

#define CAP_E   64
#define CAP_N   44

#define TR_BLOCKS  1024
#define GE_BLOCKS  1563
#define GNF_BLOCKS 1563
#define ZERO_BLKS  147

#define SC_PARTS   8
#define SC_SUB     256
#define SC_BLOCKS  (SC_PARTS * SC_SUB)   // 2048
#define SC_CHUNK   (NNZ_E / SC_SUB)      // 3125
#define E_SLICE    (E_HYPER / SC_PARTS)  // 6250
#define N_SLICE    (N_USERS / SC_PARTS)  // 12500

typedef __bf16 bf16x8 __attribute__((ext_vector_type(8)));
typedef float  f32x4  __attribute__((ext_vector_type(4)));

// ---------------------------------------------------------------------------
__device__ __forceinline__ float ld_in(const void* p, size_t i, int f32)
{
    return f32 ? ((const float*)p)[i]
               : __bfloat162float(((const __hip_bfloat16*)p)[i]);
}

// carry store: f32-in-dout(f=1) | f32-in-ws | bf16-in-dout
__device__ __forceinline__ void st_carry(void* out, float* cws, size_t i,
                                         int f, int use_ws, float v)
{
    if (f) { ((float*)out)[i] = v; return; }
    if (use_ws) { cws[i] = v; return; }
    ((__hip_bfloat16*)out)[i] = __float2bfloat16(v);
}

// ---------------------------------------------------------------------------
// Kernel 0: input dtype detector
// ---------------------------------------------------------------------------
__global__ void k_detect(const unsigned short* __restrict__ raw, int* __restrict__ flag)
{
    __shared__ int cnt;
    if (threadIdx.x == 0) cnt = 0;
    __syncthreads();
    int c = 0;
    for (int i = threadIdx.x; i < 4096; i += blockDim.x) {
        int e = (raw[i] >> 7) & 0xFF;
        if (e > 126) c++;
    }
    atomicAdd(&cnt, c);
    __syncthreads();
    if (threadIdx.x == 0) *flag = (cnt > 64) ? 1 : 0;
}

// ---------------------------------------------------------------------------
// Kernel 0b: params -> fp32 staging
// st: W[0,4096) b[4096,4160) w1[4160,8256) b1[8256,8320) w2[8320,8384) b2[8384]
// ---------------------------------------------------------------------------
__global__ void k_convert_params(
    const void* W, const void* b, const void* w1, const void* b1,
    const void* w2, const void* b2, const int* __restrict__ flag,
    float* __restrict__ st)
{
    int f = *flag;
    int i = blockIdx.x * blockDim.x + threadIdx.x;
    if (i < 4096)          st[i] = ld_in(W,  i,        f);
    else if (i < 4160)     st[i] = ld_in(b,  i - 4096, f);
    else if (i < 8256)     st[i] = ld_in(w1, i - 4160, f);
    else if (i < 8320)     st[i] = ld_in(b1, i - 8256, f);
    else if (i < 8384)     st[i] = ld_in(w2, i - 8320, f);
    else if (i == 8384)    st[i] = ld_in(b2, 0,        f);
}

// ---------------------------------------------------------------------------
// Padded atomic-append (hist+scatter fused, XCD-partitioned writes).
// counts slab layout: [0,E_HYPER) = per-hyperedge, [E_HYPER,+N_USERS) = per-node.
// rank = atomicAdd(count) doubles as slot index: ONE atomic pass per list.
// ---------------------------------------------------------------------------
__device__ __forceinline__ void appendE_body(
    const int* __restrict__ nodes, const int* __restrict__ hyper,
    int* __restrict__ cnt, int* __restrict__ sn_pad, int bid, int tid)
{
    int part = bid & (SC_PARTS - 1);
    int sub  = bid >> 3;
    int elo  = part * E_SLICE;
    int i0   = sub * SC_CHUNK;
    for (int i = i0 + tid; i < i0 + SC_CHUNK; i += 256) {
        int hy = hyper[i];
        if ((unsigned)(hy - elo) < (unsigned)E_SLICE) {
            int r = atomicAdd(&cnt[hy], 1);
            if (r < CAP_E) sn_pad[hy * CAP_E + r] = nodes[i];
        }
    }
}

__device__ __forceinline__ void appendN_body(
    const int* __restrict__ nodes, const int* __restrict__ hyper,
    int* __restrict__ cnt, int* __restrict__ sh_pad, int bid, int tid)
{
    int part = bid & (SC_PARTS - 1);
    int sub  = bid >> 3;
    int nlo  = part * N_SLICE;
    int i0   = sub * SC_CHUNK;
    for (int i = i0 + tid; i < i0 + SC_CHUNK; i += 256) {
        int nd = nodes[i];
        if ((unsigned)(nd - nlo) < (unsigned)N_SLICE) {
            int r = atomicAdd(&cnt[E_HYPER + nd], 1);
            if (r < CAP_N) sh_pad[nd * CAP_N + r] = hyper[i];
        }
    }
}

__device__ __forceinline__ void zero_body(int* __restrict__ buf, int b, int tid)
{
    int idx = b * 256 + tid;
    if (idx < 150000 / 4) ((int4*)buf)[idx] = make_int4(0, 0, 0, 0);
}

// ---------------------------------------------------------------------------
// gather_e body (padded CSR, 8 segments/wave — R2-proven loop shape)
// ---------------------------------------------------------------------------
__device__ __forceinline__ void ge_body(
    const __hip_bfloat16* __restrict__ h,
    const int* __restrict__ sn_pad, const int* __restrict__ cnt_e,
    __hip_bfloat16* __restrict__ e, int bid, int tid)
{
    int lane = tid & 63;
    int wid = bid * 4 + (tid >> 6);
    int nW  = GE_BLOCKS * 4;
    for (int s0 = wid * 8; s0 < E_HYPER; s0 += nW * 8) {
        int pos[8], end8[8], cnt8[8]; float acc[8];
#pragma unroll
        for (int c = 0; c < 8; ++c) {
            int sg = s0 + c;
            int cc = (sg < E_HYPER) ? cnt_e[sg] : 0;
            cnt8[c] = cc;
            pos[c]  = sg * CAP_E;
            end8[c] = pos[c] + min(cc, CAP_E);
            acc[c]  = 0.f;
        }
        while (true) {
            bool any = false;
#pragma unroll
            for (int c = 0; c < 8; ++c) any = any || (pos[c] < end8[c]);
            if (!any) break;
            int id[8];
#pragma unroll
            for (int c = 0; c < 8; ++c)
                if (pos[c] < end8[c]) id[c] = sn_pad[pos[c]];
#pragma unroll
            for (int c = 0; c < 8; ++c)
                if (pos[c] < end8[c]) {
                    acc[c] += __bfloat162float(h[(size_t)id[c] * DIM + lane]);
                    pos[c]++;
                }
        }
#pragma unroll
        for (int c = 0; c < 8; ++c) {
            int sg = s0 + c;
            if (sg < E_HYPER)
                e[(size_t)sg * DIM + lane] =
                    __float2bfloat16(acc[c] / (float)max(cnt8[c], 1));
        }
    }
}

// ---------------------------------------------------------------------------
// fuse tile: ONE 16-row tile at global rows [row0,row0+16), dy from LDS
// (stride 68 floats). Math verbatim from R5/R7-proven fu_body.
// ---------------------------------------------------------------------------
__device__ __forceinline__ void fu_tile(
    void* __restrict__ dout, float* __restrict__ cws,
    const float* __restrict__ dyl_t, const float* __restrict__ st,
    int f, int use_ws, int write_out, int row0, int tid)
{
    float* cf = f ? (float*)dout : (use_ws ? cws : (float*)0);
    __hip_bfloat16* cb = (__hip_bfloat16*)dout;

    int lane = tid & 63;
    int quad = lane >> 4;
    int m    = lane & 15;

    bf16x8 bw[4][2];
    float b1v[4], w2v[4];
#pragma unroll
    for (int nt = 0; nt < 4; ++nt) {
#pragma unroll
        for (int kb = 0; kb < 2; ++kb)
#pragma unroll
            for (int j = 0; j < 8; ++j) {
                int k = kb * 32 + quad * 8 + j;
                bw[nt][kb][j] = (__bf16)st[4160 + k * 64 + nt * 16 + m];
            }
        b1v[nt] = st[8256 + nt * 16 + m];
        w2v[nt] = st[8320 + nt * 16 + m];
    }

    int row = row0 + m;
    size_t base = (size_t)row * DIM;

    float hidf[2][8], dyf[2][8];
    const f32x4* dp = (const f32x4*)(dyl_t + m * 68);
    if (cf) {
        const f32x4* cp = (const f32x4*)(cf + base);
#pragma unroll
        for (int kb = 0; kb < 2; ++kb) {
            f32x4 a = cp[kb * 8 + quad * 2], b = cp[kb * 8 + quad * 2 + 1];
            f32x4 c = dp[kb * 8 + quad * 2], d = dp[kb * 8 + quad * 2 + 1];
#pragma unroll
            for (int j = 0; j < 4; ++j) {
                hidf[kb][j] = a[j]; hidf[kb][4 + j] = b[j];
                dyf[kb][j]  = c[j]; dyf[kb][4 + j]  = d[j];
            }
        }
    } else {
#pragma unroll
        for (int kb = 0; kb < 2; ++kb)
#pragma unroll
            for (int j = 0; j < 8; ++j) {
                int k = kb * 32 + quad * 8 + j;
                hidf[kb][j] = __bfloat162float(cb[base + k]);
                dyf[kb][j]  = dyl_t[m * 68 + k];
            }
    }

    bf16x8 ah[2], ad[2];
#pragma unroll
    for (int kb = 0; kb < 2; ++kb)
#pragma unroll
        for (int j = 0; j < 8; ++j) {
            ah[kb][j] = (__bf16)hidf[kb][j];
            ad[kb][j] = (__bf16)dyf[kb][j];
        }

    float zh[4] = {0.f, 0.f, 0.f, 0.f};
    float zd[4] = {0.f, 0.f, 0.f, 0.f};
#pragma unroll
    for (int nt = 0; nt < 4; ++nt) {
        f32x4 acch = {0.f, 0.f, 0.f, 0.f};
        f32x4 accd = {0.f, 0.f, 0.f, 0.f};
#pragma unroll
        for (int kb = 0; kb < 2; ++kb) {
            acch = __builtin_amdgcn_mfma_f32_16x16x32_bf16(ah[kb], bw[nt][kb], acch, 0, 0, 0);
            accd = __builtin_amdgcn_mfma_f32_16x16x32_bf16(ad[kb], bw[nt][kb], accd, 0, 0, 0);
        }
#pragma unroll
        for (int reg = 0; reg < 4; ++reg) {
            zh[reg] += tanhf(acch[reg] + b1v[nt]) * w2v[nt];
            zd[reg] += tanhf(accd[reg] + b1v[nt]) * w2v[nt];
        }
    }
    float s[4];
#pragma unroll
    for (int reg = 0; reg < 4; ++reg) {
#pragma unroll
        for (int off = 1; off < 16; off <<= 1) {
            zh[reg] += __shfl_xor(zh[reg], off, 64);
            zd[reg] += __shfl_xor(zd[reg], off, 64);
        }
        float mm = fmaxf(zh[reg], zd[reg]);
        float eh = expf(zh[reg] - mm), ed = expf(zd[reg] - mm);
        s[reg] = eh / (eh + ed);
    }
    int srcl = (m >> 2) * 16;
    float s0 = __shfl(s[0], srcl, 64), s1 = __shfl(s[1], srcl, 64);
    float s2 = __shfl(s[2], srcl, 64), s3 = __shfl(s[3], srcl, 64);
    int r3 = m & 3;
    float sv = (r3 == 0) ? s0 : (r3 == 1) ? s1 : (r3 == 2) ? s2 : s3;

    if (cf) {
        f32x4* cp = (f32x4*)(cf + base);
#pragma unroll
        for (int kb = 0; kb < 2; ++kb) {
            f32x4 v0, v1;
#pragma unroll
            for (int j = 0; j < 4; ++j) {
                v0[j] = sv * hidf[kb][j]     + (1.f - sv) * dyf[kb][j];
                v1[j] = sv * hidf[kb][4 + j] + (1.f - sv) * dyf[kb][4 + j];
            }
            cp[kb * 8 + quad * 2]     = v0;
            cp[kb * 8 + quad * 2 + 1] = v1;
            if (write_out && !f) {
#pragma unroll
                for (int j = 0; j < 4; ++j) {
                    int k = kb * 32 + quad * 8 + j;
                    cb[base + k]     = __float2bfloat16(v0[j]);
                    cb[base + k + 4] = __float2bfloat16(v1[j]);
                }
            }
        }
    } else {
#pragma unroll
        for (int kb = 0; kb < 2; ++kb)
#pragma unroll
            for (int j = 0; j < 8; ++j) {
                int k = kb * 32 + quad * 8 + j;
                float v = sv * hidf[kb][j] + (1.f - sv) * dyf[kb][j];
                cb[base + k] = __float2bfloat16(v);
            }
    }
}

// ---------------------------------------------------------------------------
// Prologue: zero counts slabs 0 and 1
// ---------------------------------------------------------------------------
__global__ __launch_bounds__(256) void k_zero2(int* __restrict__ c0, int* __restrict__ c1)
{
    if ((int)blockIdx.x < ZERO_BLKS) zero_body(c0, blockIdx.x, threadIdx.x);
    else                             zero_body(c1, blockIdx.x - ZERO_BLKS, threadIdx.x);
}

// ---------------------------------------------------------------------------
// Prologue: transform || append-E(0)
// ---------------------------------------------------------------------------
__global__ __launch_bounds__(256) void k_trans_appendE(
    const void* __restrict__ emb, const int* __restrict__ flag,
    const float* __restrict__ st, __hip_bfloat16* __restrict__ h,
    const int* __restrict__ nodes, const int* __restrict__ hyper,
    int* __restrict__ cnt, int* __restrict__ sn_pad)
{
    __shared__ float Wl[DIM * DIM];
    __shared__ float bl[DIM];
    if ((int)blockIdx.x < TR_BLOCKS) {
        for (int i = threadIdx.x; i < DIM * DIM; i += blockDim.x) Wl[i] = st[i];
        if (threadIdx.x < DIM) bl[threadIdx.x] = st[4096 + threadIdx.x];
        __syncthreads();
        int f = *flag;
        int wave = threadIdx.x >> 6, lane = threadIdx.x & 63;
        int nW = TR_BLOCKS * 4;
        for (int row = blockIdx.x * 4 + wave; row < N_USERS; row += nW) {
            size_t base = (size_t)row * DIM;
            float v = ld_in(emb, base + lane, f);
            float acc = bl[lane];
#pragma unroll
            for (int k = 0; k < DIM; ++k)
                acc += __shfl(v, k, 64) * Wl[k * DIM + lane];
            h[base + lane] = __float2bfloat16(fmaxf(acc, 0.f));
        }
    } else {
        appendE_body(nodes, hyper, cnt, sn_pad,
                     blockIdx.x - TR_BLOCKS, threadIdx.x);
    }
}

// ---------------------------------------------------------------------------
// KA: gather_e(t) || append-N(t)   (same list: sh_pad written here, read in KB)
// ---------------------------------------------------------------------------
__global__ __launch_bounds__(256) void k_ge_appendN(
    const __hip_bfloat16* __restrict__ h,
    const int* __restrict__ sn_pad, const int* __restrict__ cnt_cur,
    __hip_bfloat16* __restrict__ e,
    const int* __restrict__ nodes, const int* __restrict__ hyper,
    int* __restrict__ cnt_w, int* __restrict__ sh_pad)
{
    if ((int)blockIdx.x < GE_BLOCKS)
        ge_body(h, sn_pad, cnt_cur, e, blockIdx.x, threadIdx.x);
    else
        appendN_body(nodes, hyper, cnt_w, sh_pad,
                     blockIdx.x - GE_BLOCKS, threadIdx.x);
}

// ---------------------------------------------------------------------------
// KB: gnfuse(t) || append-E(t+1) || zero(counts for t+2)
// gnfuse R5: each WAVE owns one 16-row fuse tile; gathers all 16 rows as
// PARALLEL chains (16 outstanding loads/wave — R4's two sequential 8-batches
// halved MLP), parks dy in a wave-PRIVATE LDS strip, and fuses immediately.
// No __syncthreads: no inter-wave max-of-Poisson barrier stall.
// ---------------------------------------------------------------------------
__global__ __launch_bounds__(256) void k_gnfuse(
    const __hip_bfloat16* __restrict__ e,
    const int* __restrict__ sh_pad, const int* __restrict__ cnt_n,
    void* __restrict__ dout, float* __restrict__ cws,
    const float* __restrict__ st, const int* __restrict__ flag,
    int use_ws, int to_carry, int write_out,
    const int* __restrict__ nodes1, const int* __restrict__ hyper1,
    int* __restrict__ cnt_nxt, int* __restrict__ sn_pad, int nsc,
    int* __restrict__ cnt_zero, int nzero)
{
    __shared__ float dyl[4 * 16 * 68];   // 4 wave-private strips
    int b = blockIdx.x, tid = threadIdx.x;
    if (b < GNF_BLOCKS) {
        int f = *flag;
        int lane = tid & 63, w = tid >> 6;
        int wid  = b * 4 + w;
        int row0 = wid * 16;
        if (row0 >= N_USERS) return;

        int pos[16], rem[16], cnt16[16]; float acc[16];
#pragma unroll
        for (int c = 0; c < 16; ++c) {
            int sg = row0 + c;
            int cc = (sg < N_USERS) ? cnt_n[sg] : 0;
            cnt16[c] = cc;
            pos[c]   = sg * CAP_N;
            rem[c]   = min(cc, CAP_N);
            acc[c]   = 0.f;
        }
        while (true) {
            bool any = false;
#pragma unroll
            for (int c = 0; c < 16; ++c) any = any || (rem[c] > 0);
            if (!any) break;
            int hy[16];
#pragma unroll
            for (int c = 0; c < 16; ++c)
                if (rem[c] > 0) hy[c] = sh_pad[pos[c]];
#pragma unroll
            for (int c = 0; c < 16; ++c)
                if (rem[c] > 0) {
                    acc[c] += __bfloat162float(e[(size_t)hy[c] * DIM + lane]);
                    pos[c]++; rem[c]--;
                }
        }
#pragma unroll
        for (int c = 0; c < 16; ++c) {
            int sg = row0 + c;
            if (sg < N_USERS) {
                float v = acc[c] / (float)max(cnt16[c], 1);
                if (to_carry)
                    st_carry(dout, cws, (size_t)sg * DIM + lane, f, use_ws, v);
                else
                    dyl[(w * 16 + c) * 68 + lane] = v;
            }
        }
        if (!to_carry && row0 + 16 <= N_USERS)
            fu_tile(dout, cws, dyl + w * 16 * 68, st, f, use_ws,
                    write_out, row0, tid);
    } else if (b < GNF_BLOCKS + nsc) {
        appendE_body(nodes1, hyper1, cnt_nxt, sn_pad, b - GNF_BLOCKS, tid);
    } else if (nzero) {
        zero_body(cnt_zero, b - GNF_BLOCKS - nsc, tid);
    }
}

// ---------------------------------------------------------------------------
extern "C" void kernel_launch(void* const* d_in, const int* in_sizes, int n_in,
                              void* d_out, int out_size, void* d_ws,
                              size_t ws_size, hipStream_t stream)
{
    const void* user_emb = d_in[0];
    const void* W_conv   = d_in[1];
    const void* b_conv   = d_in[2];
    const void* fus_w1   = d_in[3];
    const void* fus_b1   = d_in[4];
    const void* fus_w2   = d_in[5];
    const void* fus_b2   = d_in[6];
    const int* edge_nodes = (const int*)d_in[7];
    const int* edge_hyper = (const int*)d_in[8];

    const size_t ND = (size_t)N_USERS * DIM;

    // ws layout (fp32 word offsets) — mandatory 51.4 MB, with carry 77.03 MB:
    //   0         : flag
    //   16        : st [8448]
    //   8464      : counts 3 slabs x 150016 ints (e[0,50K) | n[50K,150K))
    //   458512    : sn_pad int [50000*64]   (single-buffered, see schedule)
    //   3658512   : sh_pad int [100000*44]
    //   8058512   : e bf16 [E*D]
    //   9658512   : h bf16 [N*D]
    //   12858512  : optional fp32 carry [N*D]
    float* ws = (float*)d_ws;
    int*   flag   = (int*)ws;
    float* st     = ws + 16;
    int*   cnts[3];
    cnts[0] = (int*)(ws + 8464);
    cnts[1] = (int*)(ws + 8464 + 150016);
    cnts[2] = (int*)(ws + 8464 + 300032);
    int*   sn_pad = (int*)(ws + 458512);
    int*   sh_pad = (int*)(ws + 3658512);
    __hip_bfloat16* e_buf = (__hip_bfloat16*)(ws + 8058512);
    __hip_bfloat16* h     = (__hip_bfloat16*)(ws + 9658512);
    float* carry_ws       = ws + 12858512;

    const size_t need_ws_carry = (12858512 + ND) * 4;
    const int use_ws = (ws_size >= need_ws_carry) ? 1 : 0;

    k_detect<<<1, 256, 0, stream>>>((const unsigned short*)user_emb, flag);
    k_convert_params<<<(8385 + 255) / 256, 256, 0, stream>>>(
        W_conv, b_conv, fus_w1, fus_b1, fus_w2, fus_b2, flag, st);

    // prologue: zero cnt[0],cnt[1]; transform || append-E(0)
    k_zero2<<<2 * ZERO_BLKS, 256, 0, stream>>>(cnts[0], cnts[1]);
    k_trans_appendE<<<TR_BLOCKS + SC_BLOCKS, 256, 0, stream>>>(
        user_emb, flag, st, h, edge_nodes, edge_hyper, cnts[0], sn_pad);

    for (int t = 0; t < T_STEPS; ++t) {
        const int* nodes0 = edge_nodes + (size_t)t * NNZ_E;
        const int* hyper0 = edge_hyper + (size_t)t * NNZ_E;
        const int* nodes1 = edge_nodes + (size_t)(t + 1) * NNZ_E;
        const int* hyper1 = edge_hyper + (size_t)(t + 1) * NNZ_E;
        int c3 = t % 3, n3 = (t + 1) % 3, z3 = (t + 2) % 3;

        // KA: ge(t) || append-N(t)  (sh_pad for list t, read next dispatch)
        k_ge_appendN<<<GE_BLOCKS + SC_BLOCKS, 256, 0, stream>>>(
            h, sn_pad, cnts[c3], e_buf, nodes0, hyper0, cnts[c3], sh_pad);

        // KB: gnfuse(t) || append-E(t+1) || zero(cnt for t+2)
        int nsc = (t < T_STEPS - 1) ? SC_BLOCKS : 0;
        int nz  = (t < T_STEPS - 2) ? ZERO_BLKS : 0;
        k_gnfuse<<<GNF_BLOCKS + nsc + nz, 256, 0, stream>>>(
            e_buf, sh_pad, cnts[c3] + E_HYPER,
            d_out, carry_ws, st, flag, use_ws,
            (t == 0) ? 1 : 0, (t == T_STEPS - 1) ? 1 : 0,
            nodes1, hyper1, cnts[n3], sn_pad, nsc, cnts[z3], nz);
    }
}